// Round 4
// baseline (414.462 us; speedup 1.0000x reference)
//
#include <hip/hip_runtime.h>
#include <math.h>

typedef __attribute__((ext_vector_type(8))) short short8;
typedef __attribute__((ext_vector_type(4))) short short4v;
typedef __attribute__((ext_vector_type(4))) float f32x4;

#define EPSF 1e-5f

__device__ __forceinline__ short f2bf(float f) {
    union { float f; unsigned u; } v; v.f = f;
    unsigned r = (v.u + 0x7FFFu + ((v.u >> 16) & 1u)) >> 16;
    return (short)r;
}

__device__ __forceinline__ void gload16(const void* g, void* l) {
    __builtin_amdgcn_global_load_lds(
        (const __attribute__((address_space(1))) unsigned int*)g,
        (__attribute__((address_space(3))) unsigned int*)l, 16, 0, 0);
}

// ---------------- prep: xprep (blocks 0..8191) + wprep (blocks 8192..8575) ----------------
// xbf/xtbf chunk layout (1 KB each): chunk C = (b*32 + R)*16 + kt; element (l*8+e) holds
//   X[R*16 + (l&15)][kt*32 + (l>>4)*8 + e]   (xtbf: same formula on X^T)
// wcat chunk = ((side*4+d)*8 + ns)*16 + kt; elem (l*8+e) = W[n=ns*16+(l&15)][k=kt*32+(l>>4)*8+e]
// wpt chunk = (((side*4+d)*4 + mt)*4 + kk)*4 + nq; elem = p_w[r=mt*128+kk*32+(l>>4)*8+e][q=nq*16+(l&15)]
__global__ __launch_bounds__(256) void prep_kernel(
    const float* __restrict__ x,
    const float* __restrict__ o_xj, const float* __restrict__ o_xi,
    const float* __restrict__ p_xj, const float* __restrict__ p_xi,
    const float* __restrict__ o_rel_xj, const float* __restrict__ o_rel_xi,
    short* __restrict__ xbf, short* __restrict__ xtbf,
    double* __restrict__ part, short* __restrict__ wcat, short* __restrict__ wpt) {
    int tid = threadIdx.x;
    if (blockIdx.x < 8192) {
        int blk = blockIdx.x;               // 128 b * 64 tiles
        int b = blk >> 6, t = blk & 63;
        int tr = (t >> 3) * 64, tc = (t & 7) * 64;
        const float* X = x + (size_t)b * 262144;
        __shared__ short tileR[64][80];
        __shared__ double rs[256], rq[256];

        {
            int r = tid >> 2, cseg = (tid & 3) * 16;
            const float* src = X + (size_t)(tr + r) * 512 + tc + cseg;
            double s = 0.0, sq = 0.0;
            short vals[16];
            #pragma unroll
            for (int q = 0; q < 4; q++) {
                float4 f = *(const float4*)(src + q * 4);
                vals[q * 4 + 0] = f2bf(f.x); vals[q * 4 + 1] = f2bf(f.y);
                vals[q * 4 + 2] = f2bf(f.z); vals[q * 4 + 3] = f2bf(f.w);
                s += (double)f.x + (double)f.y + (double)f.z + (double)f.w;
                sq += (double)f.x * f.x + (double)f.y * f.y + (double)f.z * f.z + (double)f.w * f.w;
            }
            *(short8*)&tileR[r][cseg]     = *(short8*)&vals[0];
            *(short8*)&tileR[r][cseg + 8] = *(short8*)&vals[8];
            rs[tid] = s; rq[tid] = sq;
        }
        __syncthreads();
        for (int st = 128; st > 0; st >>= 1) {
            if (tid < st) { rs[tid] += rs[tid + st]; rq[tid] += rq[tid + st]; }
            __syncthreads();
        }
        if (tid == 0) { part[blk * 2] = rs[0]; part[blk * 2 + 1] = rq[0]; }

        int w = tid >> 6, l = tid & 63, li = l & 15, lg = l >> 4;
        #pragma unroll
        for (int q = 0; q < 2; q++) {
            int cc = w * 2 + q;
            int Rl = cc >> 1, ktl = cc & 1;
            short8 v = *(const short8*)&tileR[Rl * 16 + li][ktl * 32 + lg * 8];
            size_t chunk = (size_t)(b * 32 + (tr >> 4) + Rl) * 16 + (tc >> 5) + ktl;
            *(short8*)(xbf + chunk * 512 + l * 8) = v;
        }
        #pragma unroll
        for (int q = 0; q < 2; q++) {
            int cc = w * 2 + q;
            int Rl = cc >> 1, ktl = cc & 1;
            int c_loc = Rl * 16 + li;
            int rbase = ktl * 32 + lg * 8;
            short8 v;
            #pragma unroll
            for (int e = 0; e < 8; e++) v[e] = tileR[rbase + e][c_loc];
            size_t chunk = (size_t)(b * 32 + (tc >> 4) + Rl) * 16 + (tr >> 5) + ktl;
            *(short8*)(xtbf + chunk * 512 + l * 8) = v;
        }
    } else {
        int idx = (blockIdx.x - 8192) * 256 + tid;   // 98304 pieces
        if (idx < 65536) {
            int l = idx & 63; int chunk = idx >> 6;
            int kt = chunk & 15, ns = (chunk >> 4) & 7, sd = chunk >> 7;
            int side = sd >> 2, dd = sd & 3;
            int n = ns * 16 + (l & 15);
            int k = kt * 32 + (l >> 4) * 8;
            const float* src = (n < 64) ? (side ? o_rel_xi : o_rel_xj)
                                        : (side ? o_xi : o_xj);
            src += (size_t)dd * 32768 + (n & 63);
            short8 v;
            #pragma unroll
            for (int e = 0; e < 8; e++) v[e] = f2bf(src[(size_t)(k + e) * 64]);
            *(short8*)(wcat + (size_t)chunk * 512 + l * 8) = v;
        } else {
            int j = idx - 65536;
            int l = j & 63; int chunk = j >> 6;
            int nq = chunk & 3, kk = (chunk >> 2) & 3, mt = (chunk >> 4) & 3, sd = chunk >> 6;
            int side = sd >> 2, dd = sd & 3;
            int q = nq * 16 + (l & 15);
            int r = mt * 128 + kk * 32 + (l >> 4) * 8;
            const float* src = (side ? p_xi : p_xj) + (size_t)dd * 32768 + q;
            short8 v;
            #pragma unroll
            for (int e = 0; e < 8; e++) v[e] = f2bf(src[(size_t)(r + e) * 64]);
            *(short8*)(wpt + (size_t)chunk * 512 + l * 8) = v;
        }
    }
}

// ---------------- stats (fallback p1; p2 used by both paths) ----------------
__global__ __launch_bounds__(256) void stats_p1(const float* __restrict__ x,
                                                double* __restrict__ part) {
    int blk = blockIdx.x;  // 512
    const float4* X = (const float4*)(x + (size_t)blk * 65536);
    double s = 0.0, sq = 0.0;
    for (int i = threadIdx.x; i < 16384; i += 256) {
        float4 v = X[i];
        s += (double)v.x + (double)v.y + (double)v.z + (double)v.w;
        sq += (double)v.x * v.x + (double)v.y * v.y + (double)v.z * v.z + (double)v.w * v.w;
    }
    __shared__ double rs[256], rq[256];
    rs[threadIdx.x] = s; rq[threadIdx.x] = sq;
    __syncthreads();
    for (int st = 128; st > 0; st >>= 1) {
        if (threadIdx.x < st) { rs[threadIdx.x] += rs[threadIdx.x + st]; rq[threadIdx.x] += rq[threadIdx.x + st]; }
        __syncthreads();
    }
    if (threadIdx.x == 0) { part[blk * 2] = rs[0]; part[blk * 2 + 1] = rq[0]; }
}

__global__ void stats_p2(const double* __restrict__ part, float* __restrict__ stats, int ppb) {
    int b = threadIdx.x;  // 128
    double s = 0.0, sq = 0.0;
    for (int p = 0; p < ppb; p++) { s += part[(b * ppb + p) * 2]; sq += part[(b * ppb + p) * 2 + 1]; }
    double n = 262144.0;
    double mean = s / n;
    double var = (sq - n * mean * mean) / (n - 1.0);
    stats[b * 2 + 0] = (float)(mean * 64.0);
    stats[b * 2 + 1] = (float)(sqrt(var) * 64.0);
}

// ---------------- main MFMA kernel: one block per (b, side, d), XCD-swizzled, BK=64 ----------------
__global__ __launch_bounds__(256, 3) void main_mfma_kernel(
    const short* __restrict__ xbf, const short* __restrict__ xtbf,
    const short* __restrict__ wcat, const short* __restrict__ wpt,
    float* __restrict__ relsum, float* __restrict__ pt) {
    int blk = blockIdx.x;
    int xcd = blk & 7, rest = blk >> 3;
    int d = rest & 3, side = (rest >> 2) & 1, bhi = rest >> 3;
    int b = bhi * 8 + xcd;            // all 8 blocks of batch b share blk%8 -> same XCD
    const short* Xsw = (side ? xtbf : xbf) + (size_t)b * 262144;
    const short* Wc  = wcat + (size_t)(side * 4 + d) * 65536;
    const short* Wp  = wpt + (size_t)(side * 4 + d) * 32768;

    __shared__ __align__(16) char lds[33792];
    short* Xs  = (short*)lds;              // 16 KB: chunks (s*2+t2), kt-loop phase
    short* Wsh = (short*)(lds + 16384);    // 16 KB: chunks (ns*2+t2), kt-loop phase
    short* Tos = (short*)lds;              // overlay (pt phase): 64 x 136 shorts = 17408 B
    short* Wps = (short*)(lds + 17408);    // 16 KB (pt phase)

    int tid = threadIdx.x;
    int w = tid >> 6, l = tid & 63, li = l & 15, lg = l >> 4;
    int wm = w >> 1, wn = w & 1;

    f32x4 zero4 = {0.f, 0.f, 0.f, 0.f};
    f32x4 ptacc[4];
    #pragma unroll
    for (int i = 0; i < 4; i++) ptacc[i] = zero4;
    float esum[4] = {0.f, 0.f, 0.f, 0.f};

    for (int mt = 0; mt < 4; mt++) {
        f32x4 acc[4][4];
        #pragma unroll
        for (int i = 0; i < 4; i++)
            #pragma unroll
            for (int j = 0; j < 4; j++) acc[i][j] = zero4;

        for (int ks = 0; ks < 8; ks++) {       // BK=64: two K=32 chunks per stage
            __syncthreads();                   // prev-stage reads / overlay reads done
            #pragma unroll
            for (int ii = 0; ii < 2; ii++) {
                int s = w * 2 + ii;            // 0..7: row-subtile AND n-subtile
                #pragma unroll
                for (int t2 = 0; t2 < 2; t2++) {
                    gload16(Xsw + ((size_t)((mt * 8 + s) * 16 + ks * 2 + t2)) * 512 + l * 8,
                            Xs + (s * 2 + t2) * 512);
                    gload16(Wc + ((size_t)(s * 16 + ks * 2 + t2)) * 512 + l * 8,
                            Wsh + (s * 2 + t2) * 512);
                }
            }
            __syncthreads();                   // drains vmcnt: staged data visible
            #pragma unroll
            for (int t2 = 0; t2 < 2; t2++) {
                short8 af[4], bfv[4];
                #pragma unroll
                for (int i = 0; i < 4; i++)
                    af[i] = *(const short8*)(Xs + ((wm * 4 + i) * 2 + t2) * 512 + l * 8);
                #pragma unroll
                for (int j = 0; j < 4; j++)
                    bfv[j] = *(const short8*)(Wsh + ((wn * 4 + j) * 2 + t2) * 512 + l * 8);
                #pragma unroll
                for (int i = 0; i < 4; i++)
                    #pragma unroll
                    for (int j = 0; j < 4; j++)
                        acc[i][j] = __builtin_amdgcn_mfma_f32_16x16x32_bf16(af[i], bfv[j], acc[i][j], 0, 0, 0);
            }
        }

        __syncthreads();       // all staging reads done -> overlay regions (Tos/Wps) safe
        // issue Wp tile loads (latency overlapped with epilogue VALU below)
        #pragma unroll
        for (int ii = 0; ii < 4; ii++) {
            int s4 = w * 4 + ii;   // s4 = kk*4 + nq
            gload16(Wp + ((size_t)((mt * 4 + (s4 >> 2)) * 4 + (s4 & 3))) * 512 + l * 8,
                    Wps + s4 * 512);
        }

        if (wn == 0) {
            // rel columns: exp colsum accumulation (col = j*16 + li)
            #pragma unroll
            for (int i = 0; i < 4; i++)
                #pragma unroll
                for (int j = 0; j < 4; j++)
                    esum[j] += __expf(acc[i][j][0]) + __expf(acc[i][j][1]) +
                               __expf(acc[i][j][2]) + __expf(acc[i][j][3]);
        } else {
            // o columns: write To^T[p][r_local] (bf16)
            #pragma unroll
            for (int i = 0; i < 4; i++)
                #pragma unroll
                for (int j = 0; j < 4; j++) {
                    int p = j * 16 + li;
                    int rb = wm * 64 + i * 16 + lg * 4;
                    short4v tv;
                    tv.x = f2bf(acc[i][j][0]); tv.y = f2bf(acc[i][j][1]);
                    tv.z = f2bf(acc[i][j][2]); tv.w = f2bf(acc[i][j][3]);
                    *(short4v*)(Tos + p * 136 + rb) = tv;
                }
        }
        __syncthreads();       // Tos visible + Wps vmcnt drained

        // p_t += To^T @ Wp : wave w owns p rows w*16..w*16+15
        #pragma unroll
        for (int kk = 0; kk < 4; kk++) {
            short8 a = *(const short8*)(Tos + (w * 16 + li) * 136 + kk * 32 + lg * 8);
            #pragma unroll
            for (int nq = 0; nq < 4; nq++) {
                short8 bb = *(const short8*)(Wps + (kk * 4 + nq) * 512 + l * 8);
                ptacc[nq] = __builtin_amdgcn_mfma_f32_16x16x32_bf16(a, bb, ptacc[nq], 0, 0, 0);
            }
        }
    }

    __syncthreads();
    float* red = (float*)lds;
    if (wn == 0) {
        #pragma unroll
        for (int j = 0; j < 4; j++) red[wm * 256 + l * 4 + j] = esum[j];
    }
    __syncthreads();
    size_t base = (size_t)(b * 2 + side) * 4 + d;
    if (tid < 64) {
        float s = 0.f;
        #pragma unroll
        for (int w2 = 0; w2 < 2; w2++)
            #pragma unroll
            for (int g = 0; g < 4; g++)
                s += red[w2 * 256 + (g * 16 + (tid & 15)) * 4 + (tid >> 4)];
        float tot = s;
        #pragma unroll
        for (int off = 1; off < 64; off <<= 1) tot += __shfl_xor(tot, off, 64);
        relsum[base * 64 + tid] = s / tot;
    }
    float* ptout = pt + base * 4096;
    #pragma unroll
    for (int nq = 0; nq < 4; nq++)
        #pragma unroll
        for (int r = 0; r < 4; r++)
            ptout[(size_t)(w * 16 + lg * 4 + r) * 64 + nq * 16 + li] = ptacc[nq][r];
}

// ---------------- fallback fp32 fused kernel (round-1, proven) ----------------
__global__ __launch_bounds__(256) void fused_proj_kernel(
    const float* __restrict__ x,
    const float* __restrict__ o_xj, const float* __restrict__ o_xi,
    const float* __restrict__ p_xj, const float* __restrict__ p_xi,
    const float* __restrict__ o_rel_xj, const float* __restrict__ o_rel_xi,
    float* __restrict__ relsum, float* __restrict__ pt)
{
    int blk = blockIdx.x;
    int b = blk >> 3;
    int side = (blk >> 2) & 1;
    int d = blk & 3;

    const float* Wrel = (side ? o_rel_xi : o_rel_xj) + (size_t)d * (512 * 64);
    const float* Wo   = (side ? o_xi     : o_xj)     + (size_t)d * (512 * 64);
    const float* Wp   = (side ? p_xi     : p_xj)     + (size_t)d * (512 * 64);
    const float* X = x + (size_t)b * (512 * 512);

    __shared__ float Xs[16][68];
    __shared__ float Ws[16][128];
    __shared__ float To[64][68];
    __shared__ float Wps[64][68];
    __shared__ float red[16][64];
    __shared__ float cs[64];
    __shared__ float total_s;

    int tid = threadIdx.x;
    int tx = tid & 15;
    int ty = tid >> 4;

    float paccum[4][4];
    #pragma unroll
    for (int i = 0; i < 4; i++)
        #pragma unroll
        for (int j = 0; j < 4; j++) paccum[i][j] = 0.f;
    float esum[8];
    #pragma unroll
    for (int j = 0; j < 8; j++) esum[j] = 0.f;

    for (int r0 = 0; r0 < 512; r0 += 64) {
        float acc[4][8];
        #pragma unroll
        for (int i = 0; i < 4; i++)
            #pragma unroll
            for (int j = 0; j < 8; j++) acc[i][j] = 0.f;

        for (int k0 = 0; k0 < 512; k0 += 16) {
            if (side == 0) {
                int kk = tid & 15, r = tid >> 4;
                #pragma unroll
                for (int it = 0; it < 4; it++, r += 16)
                    Xs[kk][r] = X[(size_t)(r0 + r) * 512 + (k0 + kk)];
            } else {
                int r = tid & 63, kk = tid >> 6;
                #pragma unroll
                for (int it = 0; it < 4; it++, kk += 4)
                    Xs[kk][r] = X[(size_t)(k0 + kk) * 512 + (r0 + r)];
            }
            {
                int c = tid & 127, kk = tid >> 7;
                const float* Wsrc = (c < 64) ? (Wrel + c) : (Wo + (c - 64));
                #pragma unroll
                for (int it = 0; it < 8; it++, kk += 2)
                    Ws[kk][c] = Wsrc[(size_t)(k0 + kk) * 64];
            }
            __syncthreads();
            #pragma unroll
            for (int kk = 0; kk < 16; kk++) {
                float4 a  = *(const float4*)&Xs[kk][ty * 4];
                float4 b0 = *(const float4*)&Ws[kk][tx * 8];
                float4 b1 = *(const float4*)&Ws[kk][tx * 8 + 4];
                float av[4] = {a.x, a.y, a.z, a.w};
                float bv[8] = {b0.x, b0.y, b0.z, b0.w, b1.x, b1.y, b1.z, b1.w};
                #pragma unroll
                for (int i = 0; i < 4; i++)
                    #pragma unroll
                    for (int j = 0; j < 8; j++)
                        acc[i][j] = fmaf(av[i], bv[j], acc[i][j]);
            }
            __syncthreads();
        }

        if (tx < 8) {
            #pragma unroll
            for (int i = 0; i < 4; i++)
                #pragma unroll
                for (int j = 0; j < 8; j++)
                    esum[j] += expf(acc[i][j]);
        } else {
            #pragma unroll
            for (int i = 0; i < 4; i++) {
                float4 v0 = make_float4(acc[i][0], acc[i][1], acc[i][2], acc[i][3]);
                float4 v1 = make_float4(acc[i][4], acc[i][5], acc[i][6], acc[i][7]);
                *(float4*)&To[ty * 4 + i][(tx - 8) * 8]     = v0;
                *(float4*)&To[ty * 4 + i][(tx - 8) * 8 + 4] = v1;
            }
        }
        {
            int q = tid & 63, r = tid >> 6;
            #pragma unroll
            for (int it = 0; it < 16; it++, r += 4)
                Wps[r][q] = Wp[(size_t)(r0 + r) * 64 + q];
        }
        __syncthreads();
        for (int r = 0; r < 64; r++) {
            float4 aa = *(const float4*)&To[r][ty * 4];
            float4 bb = *(const float4*)&Wps[r][tx * 4];
            float av[4] = {aa.x, aa.y, aa.z, aa.w};
            float bv[4] = {bb.x, bb.y, bb.z, bb.w};
            #pragma unroll
            for (int i = 0; i < 4; i++)
                #pragma unroll
                for (int j = 0; j < 4; j++)
                    paccum[i][j] = fmaf(av[i], bv[j], paccum[i][j]);
        }
        __syncthreads();
    }

    if (tx < 8) {
        #pragma unroll
        for (int j = 0; j < 8; j++) red[ty][tx * 8 + j] = esum[j];
    }
    __syncthreads();
    if (tid < 64) {
        float s = 0.f;
        for (int t = 0; t < 16; t++) s += red[t][tid];
        cs[tid] = s;
    }
    __syncthreads();
    if (tid == 0) {
        float tot = 0.f;
        for (int i = 0; i < 64; i++) tot += cs[i];
        total_s = tot;
    }
    __syncthreads();
    size_t base = (size_t)(b * 2 + side) * 4 + d;
    if (tid < 64) relsum[base * 64 + tid] = cs[tid] / total_s;

    float* ptout = pt + base * 4096;
    #pragma unroll
    for (int i = 0; i < 4; i++)
        #pragma unroll
        for (int j = 0; j < 4; j++)
            ptout[(size_t)(ty * 4 + i) * 64 + tx * 4 + j] = paccum[i][j];
}

// ---------------- finalize per (b,d), writes contribution into ptj slot ----------------
__global__ __launch_bounds__(256) void finalize2_kernel(
    const float* __restrict__ relsum, float* __restrict__ pt,
    const float* __restrict__ p_rel_xj, const float* __restrict__ p_rel_xi,
    const float* __restrict__ stats)
{
    int blk = blockIdx.x;
    int b = blk >> 2, d = blk & 3;
    int tid = threadIdx.x, tx = tid & 15, ty = tid >> 4;
    __shared__ float Ptj[64][65], Pti[64][65], Wr[64][65];
    __shared__ float red[16][64];
    __shared__ float fj[64], fi[64];
    __shared__ float rs[256], rq[256];
    __shared__ float bc[1];

    float x_mean = stats[b * 2 + 0];
    float x_std  = stats[b * 2 + 1];

    float* ptj = pt + ((size_t)(b * 2 + 0) * 4 + d) * 4096;
    const float* pti = pt + ((size_t)(b * 2 + 1) * 4 + d) * 4096;
    for (int it = 0; it < 16; it++) {
        int idx = tid + it * 256;
        Ptj[idx >> 6][idx & 63] = ptj[idx];
        Pti[idx >> 6][idx & 63] = pti[idx];
    }
    __syncthreads();

    for (int s = 0; s < 2; s++) {
        const float* prel = (s == 0) ? (p_rel_xj + (size_t)d * 4096)
                                     : (p_rel_xi + (size_t)d * 4096);
        for (int it = 0; it < 16; it++) {
            int idx = tid + it * 256;
            Wr[idx >> 6][idx & 63] = prel[idx];
        }
        __syncthreads();
        float cpart[4] = {0.f, 0.f, 0.f, 0.f};
        for (int i = 0; i < 4; i++) {
            int p = ty * 4 + i;
            float q[4] = {0.f, 0.f, 0.f, 0.f};
            for (int r = 0; r < 64; r++) {
                float a = (s == 0) ? Ptj[p][r] : Pti[p][r];
                #pragma unroll
                for (int j = 0; j < 4; j++)
                    q[j] = fmaf(a, Wr[r][tx * 4 + j], q[j]);
            }
            #pragma unroll
            for (int j = 0; j < 4; j++) cpart[j] += __expf(q[j]);
        }
        #pragma unroll
        for (int j = 0; j < 4; j++) red[ty][tx * 4 + j] = cpart[j];
        __syncthreads();
        float* ftgt = (s == 0) ? fj : fi;
        if (tid < 64) {
            float cssum = 0.f;
            for (int t = 0; t < 16; t++) cssum += red[t][tid];
            ftgt[tid] = cssum;
        }
        __syncthreads();
        if (tid == 0) {
            float tot = 0.f;
            for (int i = 0; i < 64; i++) tot += ftgt[i];
            bc[0] = tot;
        }
        __syncthreads();
        if (tid < 64) {
            float prel_sum = ftgt[tid] / bc[0];
            float orel = relsum[((size_t)(b * 2 + s) * 4 + d) * 64 + tid];
            ftgt[tid] = sqrtf(orel / prel_sum);
        }
        __syncthreads();
    }

    float v[4][4];
    float psum = 0.f, psq = 0.f;
    #pragma unroll
    for (int i = 0; i < 4; i++) {
        int r = ty * 4 + i;
        #pragma unroll
        for (int j = 0; j < 4; j++) {
            int c = tx * 4 + j;
            float val = Ptj[r][c] * fj[r] + Pti[c][r] * fi[c];
            v[i][j] = val; psum += val; psq += val * val;
        }
    }
    rs[tid] = psum; rq[tid] = psq;
    __syncthreads();
    for (int st = 128; st > 0; st >>= 1) {
        if (tid < st) { rs[tid] += rs[tid + st]; rq[tid] += rq[tid + st]; }
        __syncthreads();
    }
    float mean = rs[0] / 4096.f;
    float var = (rq[0] - 4096.f * mean * mean) / 4095.f;
    float inv = 1.0f / (sqrtf(var) + EPSF);
    #pragma unroll
    for (int i = 0; i < 4; i++)
        #pragma unroll
        for (int j = 0; j < 4; j++)
            ptj[(size_t)(ty * 4 + i) * 64 + tx * 4 + j] = (v[i][j] - mean) * inv * x_std + x_mean;
}

// ---------------- sum over depth ----------------
__global__ __launch_bounds__(256) void sum_kernel(const float* __restrict__ pt,
                                                  float* __restrict__ out) {
    int b = blockIdx.x, tid = threadIdx.x;
    for (int it = 0; it < 16; it++) {
        int idx = tid + it * 256;
        float s = 0.f;
        #pragma unroll
        for (int d = 0; d < 4; d++)
            s += pt[((size_t)(b * 2) * 4 + d) * 4096 + idx];
        out[(size_t)b * 4096 + idx] = s;
    }
}

extern "C" void kernel_launch(void* const* d_in, const int* in_sizes, int n_in,
                              void* d_out, int out_size, void* d_ws, size_t ws_size,
                              hipStream_t stream) {
    const float* x        = (const float*)d_in[0];
    const float* o_xj     = (const float*)d_in[1];
    const float* o_xi     = (const float*)d_in[2];
    const float* p_xj     = (const float*)d_in[3];
    const float* p_xi     = (const float*)d_in[4];
    const float* o_rel_xj = (const float*)d_in[5];
    const float* o_rel_xi = (const float*)d_in[6];
    const float* p_rel_xj = (const float*)d_in[7];
    const float* p_rel_xi = (const float*)d_in[8];
    float* out = (float*)d_out;

    char* ws = (char*)d_ws;
    float*  stats  = (float*)(ws + 0);           // 1024
    float*  relsum = (float*)(ws + 1024);        // 262144
    float*  pt     = (float*)(ws + 263168);      // 16777216
    double* spartF = (double*)(ws + 17040384);   // 131072
    short*  xbf    = (short*)(ws + 17171456);    // 67108864
    short*  xtbf   = (short*)(ws + 84280320);    // 67108864
    short*  wcat   = (short*)(ws + 151389184);   // 1048576
    short*  wptb   = (short*)(ws + 152437760);   // 524288 -> end 152962048
    double* spartS = (double*)(ws + 263168);     // fallback alias inside pt region

    const size_t FAST_NEED = 152962048;
    if (ws_size >= FAST_NEED) {
        prep_kernel<<<8576, 256, 0, stream>>>(x, o_xj, o_xi, p_xj, p_xi,
                                              o_rel_xj, o_rel_xi,
                                              xbf, xtbf, spartF, wcat, wptb);
        stats_p2<<<1, 128, 0, stream>>>(spartF, stats, 64);
        main_mfma_kernel<<<1024, 256, 0, stream>>>(xbf, xtbf, wcat, wptb, relsum, pt);
    } else {
        stats_p1<<<512, 256, 0, stream>>>(x, spartS);
        stats_p2<<<1, 128, 0, stream>>>(spartS, stats, 4);
        fused_proj_kernel<<<1024, 256, 0, stream>>>(x, o_xj, o_xi, p_xj, p_xi,
                                                    o_rel_xj, o_rel_xi, relsum, pt);
    }
    finalize2_kernel<<<512, 256, 0, stream>>>(relsum, pt, p_rel_xj, p_rel_xi, stats);
    sum_kernel<<<128, 256, 0, stream>>>(pt, out);
}

// Round 5
// 378.320 us; speedup vs baseline: 1.0955x; 1.0955x over previous
//
#include <hip/hip_runtime.h>
#include <math.h>

typedef __attribute__((ext_vector_type(8))) short short8;
typedef __attribute__((ext_vector_type(4))) short short4v;
typedef __attribute__((ext_vector_type(4))) float f32x4;

#define EPSF 1e-5f

__device__ __forceinline__ short f2bf(float f) {
    union { float f; unsigned u; } v; v.f = f;
    unsigned r = (v.u + 0x7FFFu + ((v.u >> 16) & 1u)) >> 16;
    return (short)r;
}

__device__ __forceinline__ void gload16(const void* g, void* l) {
    __builtin_amdgcn_global_load_lds(
        (const __attribute__((address_space(1))) unsigned int*)g,
        (__attribute__((address_space(3))) unsigned int*)l, 16, 0, 0);
}

// ---------------- prep: xprep (blocks 0..8191) + wprep (blocks 8192..8575) ----------------
// xbf/xtbf chunk layout (1 KB each): chunk C = (b*32 + R)*16 + kt; element (l*8+e) holds
//   X[R*16 + (l&15)][kt*32 + (l>>4)*8 + e]   (xtbf: same formula on X^T)
// wcat chunk = ((side*4+d)*8 + ns)*16 + kt; elem (l*8+e) = W[n=ns*16+(l&15)][k=kt*32+(l>>4)*8+e]
// wpt chunk = (((side*4+d)*4 + mt)*4 + kk)*4 + nq; elem = p_w[r=mt*128+kk*32+(l>>4)*8+e][q=nq*16+(l&15)]
__global__ __launch_bounds__(256) void prep_kernel(
    const float* __restrict__ x,
    const float* __restrict__ o_xj, const float* __restrict__ o_xi,
    const float* __restrict__ p_xj, const float* __restrict__ p_xi,
    const float* __restrict__ o_rel_xj, const float* __restrict__ o_rel_xi,
    short* __restrict__ xbf, short* __restrict__ xtbf,
    double* __restrict__ part, short* __restrict__ wcat, short* __restrict__ wpt) {
    int tid = threadIdx.x;
    if (blockIdx.x < 8192) {
        int blk = blockIdx.x;               // 128 b * 64 tiles
        int b = blk >> 6, t = blk & 63;
        int tr = (t >> 3) * 64, tc = (t & 7) * 64;
        const float* X = x + (size_t)b * 262144;
        __shared__ short tileR[64][80];
        __shared__ double rs[256], rq[256];

        {
            int r = tid >> 2, cseg = (tid & 3) * 16;
            const float* src = X + (size_t)(tr + r) * 512 + tc + cseg;
            double s = 0.0, sq = 0.0;
            short vals[16];
            #pragma unroll
            for (int q = 0; q < 4; q++) {
                float4 f = *(const float4*)(src + q * 4);
                vals[q * 4 + 0] = f2bf(f.x); vals[q * 4 + 1] = f2bf(f.y);
                vals[q * 4 + 2] = f2bf(f.z); vals[q * 4 + 3] = f2bf(f.w);
                s += (double)f.x + (double)f.y + (double)f.z + (double)f.w;
                sq += (double)f.x * f.x + (double)f.y * f.y + (double)f.z * f.z + (double)f.w * f.w;
            }
            *(short8*)&tileR[r][cseg]     = *(short8*)&vals[0];
            *(short8*)&tileR[r][cseg + 8] = *(short8*)&vals[8];
            rs[tid] = s; rq[tid] = sq;
        }
        __syncthreads();
        for (int st = 128; st > 0; st >>= 1) {
            if (tid < st) { rs[tid] += rs[tid + st]; rq[tid] += rq[tid + st]; }
            __syncthreads();
        }
        if (tid == 0) { part[blk * 2] = rs[0]; part[blk * 2 + 1] = rq[0]; }

        int w = tid >> 6, l = tid & 63, li = l & 15, lg = l >> 4;
        #pragma unroll
        for (int q = 0; q < 2; q++) {
            int cc = w * 2 + q;
            int Rl = cc >> 1, ktl = cc & 1;
            short8 v = *(const short8*)&tileR[Rl * 16 + li][ktl * 32 + lg * 8];
            size_t chunk = (size_t)(b * 32 + (tr >> 4) + Rl) * 16 + (tc >> 5) + ktl;
            *(short8*)(xbf + chunk * 512 + l * 8) = v;
        }
        #pragma unroll
        for (int q = 0; q < 2; q++) {
            int cc = w * 2 + q;
            int Rl = cc >> 1, ktl = cc & 1;
            int c_loc = Rl * 16 + li;
            int rbase = ktl * 32 + lg * 8;
            short8 v;
            #pragma unroll
            for (int e = 0; e < 8; e++) v[e] = tileR[rbase + e][c_loc];
            size_t chunk = (size_t)(b * 32 + (tc >> 4) + Rl) * 16 + (tr >> 5) + ktl;
            *(short8*)(xtbf + chunk * 512 + l * 8) = v;
        }
    } else {
        int idx = (blockIdx.x - 8192) * 256 + tid;   // 98304 pieces
        if (idx < 65536) {
            int l = idx & 63; int chunk = idx >> 6;
            int kt = chunk & 15, ns = (chunk >> 4) & 7, sd = chunk >> 7;
            int side = sd >> 2, dd = sd & 3;
            int n = ns * 16 + (l & 15);
            int k = kt * 32 + (l >> 4) * 8;
            const float* src = (n < 64) ? (side ? o_rel_xi : o_rel_xj)
                                        : (side ? o_xi : o_xj);
            src += (size_t)dd * 32768 + (n & 63);
            short8 v;
            #pragma unroll
            for (int e = 0; e < 8; e++) v[e] = f2bf(src[(size_t)(k + e) * 64]);
            *(short8*)(wcat + (size_t)chunk * 512 + l * 8) = v;
        } else {
            int j = idx - 65536;
            int l = j & 63; int chunk = j >> 6;
            int nq = chunk & 3, kk = (chunk >> 2) & 3, mt = (chunk >> 4) & 3, sd = chunk >> 6;
            int side = sd >> 2, dd = sd & 3;
            int q = nq * 16 + (l & 15);
            int r = mt * 128 + kk * 32 + (l >> 4) * 8;
            const float* src = (side ? p_xi : p_xj) + (size_t)dd * 32768 + q;
            short8 v;
            #pragma unroll
            for (int e = 0; e < 8; e++) v[e] = f2bf(src[(size_t)(r + e) * 64]);
            *(short8*)(wpt + (size_t)chunk * 512 + l * 8) = v;
        }
    }
}

// ---------------- stats (fallback only) ----------------
__global__ __launch_bounds__(256) void stats_p1(const float* __restrict__ x,
                                                double* __restrict__ part) {
    int blk = blockIdx.x;  // 512
    const float4* X = (const float4*)(x + (size_t)blk * 65536);
    double s = 0.0, sq = 0.0;
    for (int i = threadIdx.x; i < 16384; i += 256) {
        float4 v = X[i];
        s += (double)v.x + (double)v.y + (double)v.z + (double)v.w;
        sq += (double)v.x * v.x + (double)v.y * v.y + (double)v.z * v.z + (double)v.w * v.w;
    }
    __shared__ double rs[256], rq[256];
    rs[threadIdx.x] = s; rq[threadIdx.x] = sq;
    __syncthreads();
    for (int st = 128; st > 0; st >>= 1) {
        if (threadIdx.x < st) { rs[threadIdx.x] += rs[threadIdx.x + st]; rq[threadIdx.x] += rq[threadIdx.x + st]; }
        __syncthreads();
    }
    if (threadIdx.x == 0) { part[blk * 2] = rs[0]; part[blk * 2 + 1] = rq[0]; }
}

__global__ void stats_p2(const double* __restrict__ part, float* __restrict__ stats, int ppb) {
    int b = threadIdx.x;  // 128
    double s = 0.0, sq = 0.0;
    for (int p = 0; p < ppb; p++) { s += part[(b * ppb + p) * 2]; sq += part[(b * ppb + p) * 2 + 1]; }
    double n = 262144.0;
    double mean = s / n;
    double var = (sq - n * mean * mean) / (n - 1.0);
    stats[b * 2 + 0] = (float)(mean * 64.0);
    stats[b * 2 + 1] = (float)(sqrt(var) * 64.0);
}

// ---------------- main MFMA kernel: round-3 version (BK=32), XCD-swizzled ----------------
__global__ __launch_bounds__(256, 3) void main_mfma_kernel(
    const short* __restrict__ xbf, const short* __restrict__ xtbf,
    const short* __restrict__ wcat, const short* __restrict__ wpt,
    float* __restrict__ relsum, float* __restrict__ pt) {
    int blk = blockIdx.x;
    int xcd = blk & 7, rest = blk >> 3;
    int d = rest & 3, side = (rest >> 2) & 1, bhi = rest >> 3;
    int b = bhi * 8 + xcd;            // all 8 blocks of batch b share blk%8 -> same XCD
    const short* Xsw = (side ? xtbf : xbf) + (size_t)b * 262144;
    const short* Wc  = wcat + (size_t)(side * 4 + d) * 65536;
    const short* Wp  = wpt + (size_t)(side * 4 + d) * 32768;

    __shared__ __align__(16) char lds[33792];
    short* Xs  = (short*)lds;              // 8 KB (kt-loop phase)
    short* Wsh = (short*)(lds + 8192);     // 8 KB (kt-loop phase)
    short* Tos = (short*)lds;              // 17408 B overlay (pt phase): 64 x 136 shorts
    short* Wps = (short*)(lds + 17408);    // 16 KB (pt phase)

    int tid = threadIdx.x;
    int w = tid >> 6, l = tid & 63, li = l & 15, lg = l >> 4;
    int wm = w >> 1, wn = w & 1;

    f32x4 zero4 = {0.f, 0.f, 0.f, 0.f};
    f32x4 ptacc[4];
    #pragma unroll
    for (int i = 0; i < 4; i++) ptacc[i] = zero4;
    float esum[4] = {0.f, 0.f, 0.f, 0.f};

    for (int mt = 0; mt < 4; mt++) {
        f32x4 acc[4][4];
        #pragma unroll
        for (int i = 0; i < 4; i++)
            #pragma unroll
            for (int j = 0; j < 4; j++) acc[i][j] = zero4;

        for (int kt = 0; kt < 16; kt++) {
            __syncthreads();
            #pragma unroll
            for (int ii = 0; ii < 4; ii++) {
                int s = w * 4 + ii;
                if (s < 8)
                    gload16(Xsw + ((size_t)((mt * 8 + s) * 16 + kt)) * 512 + l * 8, Xs + s * 512);
                else
                    gload16(Wc + ((size_t)((s - 8) * 16 + kt)) * 512 + l * 8, Wsh + (s - 8) * 512);
            }
            __syncthreads();
            short8 af[4], bfv[4];
            #pragma unroll
            for (int i = 0; i < 4; i++) af[i] = *(const short8*)(Xs + (wm * 4 + i) * 512 + l * 8);
            #pragma unroll
            for (int j = 0; j < 4; j++) bfv[j] = *(const short8*)(Wsh + (wn * 4 + j) * 512 + l * 8);
            #pragma unroll
            for (int i = 0; i < 4; i++)
                #pragma unroll
                for (int j = 0; j < 4; j++)
                    acc[i][j] = __builtin_amdgcn_mfma_f32_16x16x32_bf16(af[i], bfv[j], acc[i][j], 0, 0, 0);
        }

        // prefetch Wp tile for this mt (distinct LDS region, safe to issue now)
        #pragma unroll
        for (int ii = 0; ii < 4; ii++) {
            int s = w * 4 + ii;   // s = kk*4 + nq
            gload16(Wp + ((size_t)((mt * 4 + (s >> 2)) * 4 + (s & 3))) * 512 + l * 8, Wps + s * 512);
        }
        __syncthreads();   // drains Wp loads; all waves done reading Xs/Wsh (Tos overlay safe)

        if (wn == 0) {
            // rel columns: exp colsum accumulation (col = j*16 + li)
            #pragma unroll
            for (int i = 0; i < 4; i++)
                #pragma unroll
                for (int j = 0; j < 4; j++)
                    esum[j] += __expf(acc[i][j][0]) + __expf(acc[i][j][1]) +
                               __expf(acc[i][j][2]) + __expf(acc[i][j][3]);
        } else {
            // o columns: write To^T[p][r_local] (bf16)
            #pragma unroll
            for (int i = 0; i < 4; i++)
                #pragma unroll
                for (int j = 0; j < 4; j++) {
                    int p = j * 16 + li;
                    int rb = wm * 64 + i * 16 + lg * 4;
                    short4v tv;
                    tv.x = f2bf(acc[i][j][0]); tv.y = f2bf(acc[i][j][1]);
                    tv.z = f2bf(acc[i][j][2]); tv.w = f2bf(acc[i][j][3]);
                    *(short4v*)(Tos + p * 136 + rb) = tv;
                }
        }
        __syncthreads();   // Tos visible

        // p_t += To^T @ Wp : wave w owns p rows w*16..w*16+15
        #pragma unroll
        for (int kk = 0; kk < 4; kk++) {
            short8 a = *(const short8*)(Tos + (w * 16 + li) * 136 + kk * 32 + lg * 8);
            #pragma unroll
            for (int nq = 0; nq < 4; nq++) {
                short8 bb = *(const short8*)(Wps + (kk * 4 + nq) * 512 + l * 8);
                ptacc[nq] = __builtin_amdgcn_mfma_f32_16x16x32_bf16(a, bb, ptacc[nq], 0, 0, 0);
            }
        }
    }

    __syncthreads();
    float* red = (float*)lds;
    if (wn == 0) {
        #pragma unroll
        for (int j = 0; j < 4; j++) red[wm * 256 + l * 4 + j] = esum[j];
    }
    __syncthreads();
    size_t base = (size_t)(b * 2 + side) * 4 + d;
    if (tid < 64) {
        float s = 0.f;
        #pragma unroll
        for (int w2 = 0; w2 < 2; w2++)
            #pragma unroll
            for (int g = 0; g < 4; g++)
                s += red[w2 * 256 + (g * 16 + (tid & 15)) * 4 + (tid >> 4)];
        float tot = s;
        #pragma unroll
        for (int off = 1; off < 64; off <<= 1) tot += __shfl_xor(tot, off, 64);
        relsum[base * 64 + tid] = s / tot;
    }
    float* ptout = pt + base * 4096;
    #pragma unroll
    for (int nq = 0; nq < 4; nq++)
        #pragma unroll
        for (int r = 0; r < 4; r++)
            ptout[(size_t)(w * 16 + lg * 4 + r) * 64 + nq * 16 + li] = ptacc[nq][r];
}

// ---------------- fallback fp32 fused kernel (round-1, proven) ----------------
__global__ __launch_bounds__(256) void fused_proj_kernel(
    const float* __restrict__ x,
    const float* __restrict__ o_xj, const float* __restrict__ o_xi,
    const float* __restrict__ p_xj, const float* __restrict__ p_xi,
    const float* __restrict__ o_rel_xj, const float* __restrict__ o_rel_xi,
    float* __restrict__ relsum, float* __restrict__ pt)
{
    int blk = blockIdx.x;
    int b = blk >> 3;
    int side = (blk >> 2) & 1;
    int d = blk & 3;

    const float* Wrel = (side ? o_rel_xi : o_rel_xj) + (size_t)d * (512 * 64);
    const float* Wo   = (side ? o_xi     : o_xj)     + (size_t)d * (512 * 64);
    const float* Wp   = (side ? p_xi     : p_xj)     + (size_t)d * (512 * 64);
    const float* X = x + (size_t)b * (512 * 512);

    __shared__ float Xs[16][68];
    __shared__ float Ws[16][128];
    __shared__ float To[64][68];
    __shared__ float Wps[64][68];
    __shared__ float red[16][64];
    __shared__ float cs[64];
    __shared__ float total_s;

    int tid = threadIdx.x;
    int tx = tid & 15;
    int ty = tid >> 4;

    float paccum[4][4];
    #pragma unroll
    for (int i = 0; i < 4; i++)
        #pragma unroll
        for (int j = 0; j < 4; j++) paccum[i][j] = 0.f;
    float esum[8];
    #pragma unroll
    for (int j = 0; j < 8; j++) esum[j] = 0.f;

    for (int r0 = 0; r0 < 512; r0 += 64) {
        float acc[4][8];
        #pragma unroll
        for (int i = 0; i < 4; i++)
            #pragma unroll
            for (int j = 0; j < 8; j++) acc[i][j] = 0.f;

        for (int k0 = 0; k0 < 512; k0 += 16) {
            if (side == 0) {
                int kk = tid & 15, r = tid >> 4;
                #pragma unroll
                for (int it = 0; it < 4; it++, r += 16)
                    Xs[kk][r] = X[(size_t)(r0 + r) * 512 + (k0 + kk)];
            } else {
                int r = tid & 63, kk = tid >> 6;
                #pragma unroll
                for (int it = 0; it < 4; it++, kk += 4)
                    Xs[kk][r] = X[(size_t)(k0 + kk) * 512 + (r0 + r)];
            }
            {
                int c = tid & 127, kk = tid >> 7;
                const float* Wsrc = (c < 64) ? (Wrel + c) : (Wo + (c - 64));
                #pragma unroll
                for (int it = 0; it < 8; it++, kk += 2)
                    Ws[kk][c] = Wsrc[(size_t)(k0 + kk) * 64];
            }
            __syncthreads();
            #pragma unroll
            for (int kk = 0; kk < 16; kk++) {
                float4 a  = *(const float4*)&Xs[kk][ty * 4];
                float4 b0 = *(const float4*)&Ws[kk][tx * 8];
                float4 b1 = *(const float4*)&Ws[kk][tx * 8 + 4];
                float av[4] = {a.x, a.y, a.z, a.w};
                float bv[8] = {b0.x, b0.y, b0.z, b0.w, b1.x, b1.y, b1.z, b1.w};
                #pragma unroll
                for (int i = 0; i < 4; i++)
                    #pragma unroll
                    for (int j = 0; j < 8; j++)
                        acc[i][j] = fmaf(av[i], bv[j], acc[i][j]);
            }
            __syncthreads();
        }

        if (tx < 8) {
            #pragma unroll
            for (int i = 0; i < 4; i++)
                #pragma unroll
                for (int j = 0; j < 8; j++)
                    esum[j] += expf(acc[i][j]);
        } else {
            #pragma unroll
            for (int i = 0; i < 4; i++) {
                float4 v0 = make_float4(acc[i][0], acc[i][1], acc[i][2], acc[i][3]);
                float4 v1 = make_float4(acc[i][4], acc[i][5], acc[i][6], acc[i][7]);
                *(float4*)&To[ty * 4 + i][(tx - 8) * 8]     = v0;
                *(float4*)&To[ty * 4 + i][(tx - 8) * 8 + 4] = v1;
            }
        }
        {
            int q = tid & 63, r = tid >> 6;
            #pragma unroll
            for (int it = 0; it < 16; it++, r += 4)
                Wps[r][q] = Wp[(size_t)(r0 + r) * 64 + q];
        }
        __syncthreads();
        for (int r = 0; r < 64; r++) {
            float4 aa = *(const float4*)&To[r][ty * 4];
            float4 bb = *(const float4*)&Wps[r][tx * 4];
            float av[4] = {aa.x, aa.y, aa.z, aa.w};
            float bv[4] = {bb.x, bb.y, bb.z, bb.w};
            #pragma unroll
            for (int i = 0; i < 4; i++)
                #pragma unroll
                for (int j = 0; j < 4; j++)
                    paccum[i][j] = fmaf(av[i], bv[j], paccum[i][j]);
        }
        __syncthreads();
    }

    if (tx < 8) {
        #pragma unroll
        for (int j = 0; j < 8; j++) red[ty][tx * 8 + j] = esum[j];
    }
    __syncthreads();
    if (tid < 64) {
        float s = 0.f;
        for (int t = 0; t < 16; t++) s += red[t][tid];
        cs[tid] = s;
    }
    __syncthreads();
    if (tid == 0) {
        float tot = 0.f;
        for (int i = 0; i < 64; i++) tot += cs[i];
        total_s = tot;
    }
    __syncthreads();
    size_t base = (size_t)(b * 2 + side) * 4 + d;
    if (tid < 64) relsum[base * 64 + tid] = cs[tid] / total_s;

    float* ptout = pt + base * 4096;
    #pragma unroll
    for (int i = 0; i < 4; i++)
        #pragma unroll
        for (int j = 0; j < 4; j++)
            ptout[(size_t)(ty * 4 + i) * 64 + tx * 4 + j] = paccum[i][j];
}

// ---------------- finalize per (b,d): stats from partials, atomicAdd into out ----------------
__global__ __launch_bounds__(256) void finalize2_kernel(
    const float* __restrict__ relsum, const float* __restrict__ pt,
    const float* __restrict__ p_rel_xj, const float* __restrict__ p_rel_xi,
    const double* __restrict__ part, const float* __restrict__ stats, int ppb,
    float* __restrict__ out)
{
    int blk = blockIdx.x;
    int b = blk >> 2, d = blk & 3;
    int tid = threadIdx.x, tx = tid & 15, ty = tid >> 4;
    __shared__ float Ptj[64][65], Pti[64][65], Wr[64][65];
    __shared__ float red[16][64];
    __shared__ float fj[64], fi[64];
    __shared__ float rs[256], rq[256];
    __shared__ float bc[1];
    __shared__ float sstat[2];

    if (ppb > 0) {
        // reduce 64 fp64 partial pairs for batch b (one wave)
        if (tid < 64) {
            double s = part[(size_t)(b * 64 + tid) * 2];
            double sq = part[(size_t)(b * 64 + tid) * 2 + 1];
            #pragma unroll
            for (int off = 1; off < 64; off <<= 1) {
                s += __shfl_xor(s, off, 64);
                sq += __shfl_xor(sq, off, 64);
            }
            if (tid == 0) {
                double n = 262144.0;
                double mean = s / n;
                double var = (sq - n * mean * mean) / (n - 1.0);
                sstat[0] = (float)(mean * 64.0);
                sstat[1] = (float)(sqrt(var) * 64.0);
            }
        }
    } else if (tid == 0) {
        sstat[0] = stats[b * 2 + 0];
        sstat[1] = stats[b * 2 + 1];
    }

    const float* ptj = pt + ((size_t)(b * 2 + 0) * 4 + d) * 4096;
    const float* pti = pt + ((size_t)(b * 2 + 1) * 4 + d) * 4096;
    for (int it = 0; it < 16; it++) {
        int idx = tid + it * 256;
        Ptj[idx >> 6][idx & 63] = ptj[idx];
        Pti[idx >> 6][idx & 63] = pti[idx];
    }
    __syncthreads();
    float x_mean = sstat[0];
    float x_std  = sstat[1];

    for (int s = 0; s < 2; s++) {
        const float* prel = (s == 0) ? (p_rel_xj + (size_t)d * 4096)
                                     : (p_rel_xi + (size_t)d * 4096);
        for (int it = 0; it < 16; it++) {
            int idx = tid + it * 256;
            Wr[idx >> 6][idx & 63] = prel[idx];
        }
        __syncthreads();
        float cpart[4] = {0.f, 0.f, 0.f, 0.f};
        for (int i = 0; i < 4; i++) {
            int p = ty * 4 + i;
            float q[4] = {0.f, 0.f, 0.f, 0.f};
            for (int r = 0; r < 64; r++) {
                float a = (s == 0) ? Ptj[p][r] : Pti[p][r];
                #pragma unroll
                for (int j = 0; j < 4; j++)
                    q[j] = fmaf(a, Wr[r][tx * 4 + j], q[j]);
            }
            #pragma unroll
            for (int j = 0; j < 4; j++) cpart[j] += __expf(q[j]);
        }
        #pragma unroll
        for (int j = 0; j < 4; j++) red[ty][tx * 4 + j] = cpart[j];
        __syncthreads();
        float* ftgt = (s == 0) ? fj : fi;
        if (tid < 64) {
            float cssum = 0.f;
            for (int t = 0; t < 16; t++) cssum += red[t][tid];
            ftgt[tid] = cssum;
        }
        __syncthreads();
        if (tid == 0) {
            float tot = 0.f;
            for (int i = 0; i < 64; i++) tot += ftgt[i];
            bc[0] = tot;
        }
        __syncthreads();
        if (tid < 64) {
            float prel_sum = ftgt[tid] / bc[0];
            float orel = relsum[((size_t)(b * 2 + s) * 4 + d) * 64 + tid];
            ftgt[tid] = sqrtf(orel / prel_sum);
        }
        __syncthreads();
    }

    float v[4][4];
    float psum = 0.f, psq = 0.f;
    #pragma unroll
    for (int i = 0; i < 4; i++) {
        int r = ty * 4 + i;
        #pragma unroll
        for (int j = 0; j < 4; j++) {
            int c = tx * 4 + j;
            float val = Ptj[r][c] * fj[r] + Pti[c][r] * fi[c];
            v[i][j] = val; psum += val; psq += val * val;
        }
    }
    rs[tid] = psum; rq[tid] = psq;
    __syncthreads();
    for (int st = 128; st > 0; st >>= 1) {
        if (tid < st) { rs[tid] += rs[tid + st]; rq[tid] += rq[tid + st]; }
        __syncthreads();
    }
    float mean = rs[0] / 4096.f;
    float var = (rq[0] - 4096.f * mean * mean) / 4095.f;
    float inv = 1.0f / (sqrtf(var) + EPSF);
    float* ob = out + (size_t)b * 4096;
    #pragma unroll
    for (int i = 0; i < 4; i++)
        #pragma unroll
        for (int j = 0; j < 4; j++)
            atomicAdd(&ob[(size_t)(ty * 4 + i) * 64 + tx * 4 + j],
                      (v[i][j] - mean) * inv * x_std + x_mean);
}

extern "C" void kernel_launch(void* const* d_in, const int* in_sizes, int n_in,
                              void* d_out, int out_size, void* d_ws, size_t ws_size,
                              hipStream_t stream) {
    const float* x        = (const float*)d_in[0];
    const float* o_xj     = (const float*)d_in[1];
    const float* o_xi     = (const float*)d_in[2];
    const float* p_xj     = (const float*)d_in[3];
    const float* p_xi     = (const float*)d_in[4];
    const float* o_rel_xj = (const float*)d_in[5];
    const float* o_rel_xi = (const float*)d_in[6];
    const float* p_rel_xj = (const float*)d_in[7];
    const float* p_rel_xi = (const float*)d_in[8];
    float* out = (float*)d_out;

    char* ws = (char*)d_ws;
    float*  stats  = (float*)(ws + 0);           // 1024
    float*  relsum = (float*)(ws + 1024);        // 262144
    float*  pt     = (float*)(ws + 263168);      // 16777216
    double* spartF = (double*)(ws + 17040384);   // 131072
    short*  xbf    = (short*)(ws + 17171456);    // 67108864
    short*  xtbf   = (short*)(ws + 84280320);    // 67108864
    short*  wcat   = (short*)(ws + 151389184);   // 1048576
    short*  wptb   = (short*)(ws + 152437760);   // 524288 -> end 152962048
    double* spartS = (double*)(ws + 17040384);   // fallback reuses spartF slot (512*2 doubles)

    hipMemsetAsync(d_out, 0, (size_t)out_size * sizeof(float), stream);

    const size_t FAST_NEED = 152962048;
    if (ws_size >= FAST_NEED) {
        prep_kernel<<<8576, 256, 0, stream>>>(x, o_xj, o_xi, p_xj, p_xi,
                                              o_rel_xj, o_rel_xi,
                                              xbf, xtbf, spartF, wcat, wptb);
        main_mfma_kernel<<<1024, 256, 0, stream>>>(xbf, xtbf, wcat, wptb, relsum, pt);
        finalize2_kernel<<<512, 256, 0, stream>>>(relsum, pt, p_rel_xj, p_rel_xi,
                                                  spartF, stats, 64, out);
    } else {
        if (ws_size >= 17171456) {
            stats_p1<<<512, 256, 0, stream>>>(x, spartS);
            stats_p2<<<1, 128, 0, stream>>>(spartS, stats, 4);
        } else {
            // tiny-ws fallback: alias partials inside pt region (dead until fused writes)
            double* sp = (double*)(ws + 263168);
            stats_p1<<<512, 256, 0, stream>>>(x, sp);
            stats_p2<<<1, 128, 0, stream>>>(sp, stats, 4);
        }
        fused_proj_kernel<<<1024, 256, 0, stream>>>(x, o_xj, o_xi, p_xj, p_xi,
                                                    o_rel_xj, o_rel_xi, relsum, pt);
        finalize2_kernel<<<512, 256, 0, stream>>>(relsum, pt, p_rel_xj, p_rel_xi,
                                                  (const double*)nullptr, stats, 0, out);
    }
}

// Round 6
// 354.410 us; speedup vs baseline: 1.1694x; 1.0675x over previous
//
#include <hip/hip_runtime.h>
#include <math.h>

typedef __attribute__((ext_vector_type(8))) short short8;
typedef __attribute__((ext_vector_type(4))) short short4v;
typedef __attribute__((ext_vector_type(4))) float f32x4;

#define EPSF 1e-5f

__device__ __forceinline__ short f2bf(float f) {
    union { float f; unsigned u; } v; v.f = f;
    unsigned r = (v.u + 0x7FFFu + ((v.u >> 16) & 1u)) >> 16;
    return (short)r;
}

__device__ __forceinline__ void gload16(const void* g, void* l) {
    __builtin_amdgcn_global_load_lds(
        (const __attribute__((address_space(1))) unsigned int*)g,
        (__attribute__((address_space(3))) unsigned int*)l, 16, 0, 0);
}

// ---------------- prep: xprep (blocks 0..8191) + wprep (blocks 8192..8575) ----------------
// xbf/xtbf chunk layout (1 KB each): chunk C = (b*32 + R)*16 + kt; element (l*8+e) holds
//   X[R*16 + (l&15)][kt*32 + (l>>4)*8 + e]   (xtbf: same formula on X^T)
// tileR stride = 82 shorts (41 words, odd) -> xtbf column-gather is bank-conflict-free:
//   bank = (8*lg + 9*e + 8*Rl + li/2) % 32 covers all banks. (stride 80 gave 8-way.)
__global__ __launch_bounds__(256) void prep_kernel(
    const float* __restrict__ x,
    const float* __restrict__ o_xj, const float* __restrict__ o_xi,
    const float* __restrict__ p_xj, const float* __restrict__ p_xi,
    const float* __restrict__ o_rel_xj, const float* __restrict__ o_rel_xi,
    short* __restrict__ xbf, short* __restrict__ xtbf,
    double* __restrict__ part, short* __restrict__ wcat, short* __restrict__ wpt) {
    int tid = threadIdx.x;
    if (blockIdx.x < 8192) {
        int blk = blockIdx.x;               // 128 b * 64 tiles
        int b = blk >> 6, t = blk & 63;
        int tr = (t >> 3) * 64, tc = (t & 7) * 64;
        const float* X = x + (size_t)b * 262144;
        __shared__ short tileR[64][82];     // odd word-stride: see note above
        __shared__ double rs[256], rq[256];

        // phase 1: coalesced read, convert, stage row-major (b32 writes, 4-B aligned)
        {
            int r = tid >> 2, cseg = (tid & 3) * 16;
            const float* src = X + (size_t)(tr + r) * 512 + tc + cseg;
            double s = 0.0, sq = 0.0;
            short vals[16];
            #pragma unroll
            for (int q = 0; q < 4; q++) {
                float4 f = *(const float4*)(src + q * 4);
                vals[q * 4 + 0] = f2bf(f.x); vals[q * 4 + 1] = f2bf(f.y);
                vals[q * 4 + 2] = f2bf(f.z); vals[q * 4 + 3] = f2bf(f.w);
                s += (double)f.x + (double)f.y + (double)f.z + (double)f.w;
                sq += (double)f.x * f.x + (double)f.y * f.y + (double)f.z * f.z + (double)f.w * f.w;
            }
            int* tp = (int*)&tileR[r][cseg];
            #pragma unroll
            for (int q = 0; q < 8; q++) tp[q] = ((const int*)vals)[q];
            rs[tid] = s; rq[tid] = sq;
        }
        __syncthreads();
        for (int st = 128; st > 0; st >>= 1) {
            if (tid < st) { rs[tid] += rs[tid + st]; rq[tid] += rq[tid + st]; }
            __syncthreads();
        }
        if (tid == 0) { part[blk * 2] = rs[0]; part[blk * 2 + 1] = rq[0]; }

        int w = tid >> 6, l = tid & 63, li = l & 15, lg = l >> 4;
        #pragma unroll
        for (int q = 0; q < 2; q++) {
            int cc = w * 2 + q;
            int Rl = cc >> 1, ktl = cc & 1;
            const int* sp = (const int*)&tileR[Rl * 16 + li][ktl * 32 + lg * 8];
            int tmp[4];
            #pragma unroll
            for (int j = 0; j < 4; j++) tmp[j] = sp[j];
            size_t chunk = (size_t)(b * 32 + (tr >> 4) + Rl) * 16 + (tc >> 5) + ktl;
            *(short8*)(xbf + chunk * 512 + l * 8) = *(const short8*)tmp;
        }
        #pragma unroll
        for (int q = 0; q < 2; q++) {
            int cc = w * 2 + q;
            int Rl = cc >> 1, ktl = cc & 1;
            int c_loc = Rl * 16 + li;
            int rbase = ktl * 32 + lg * 8;
            short8 v;
            #pragma unroll
            for (int e = 0; e < 8; e++) v[e] = tileR[rbase + e][c_loc];
            size_t chunk = (size_t)(b * 32 + (tc >> 4) + Rl) * 16 + (tr >> 5) + ktl;
            *(short8*)(xtbf + chunk * 512 + l * 8) = v;
        }
    } else {
        int idx = (blockIdx.x - 8192) * 256 + tid;   // 98304 pieces
        if (idx < 65536) {
            int l = idx & 63; int chunk = idx >> 6;
            int kt = chunk & 15, ns = (chunk >> 4) & 7, sd = chunk >> 7;
            int side = sd >> 2, dd = sd & 3;
            int n = ns * 16 + (l & 15);
            int k = kt * 32 + (l >> 4) * 8;
            const float* src = (n < 64) ? (side ? o_rel_xi : o_rel_xj)
                                        : (side ? o_xi : o_xj);
            src += (size_t)dd * 32768 + (n & 63);
            short8 v;
            #pragma unroll
            for (int e = 0; e < 8; e++) v[e] = f2bf(src[(size_t)(k + e) * 64]);
            *(short8*)(wcat + (size_t)chunk * 512 + l * 8) = v;
        } else {
            int j = idx - 65536;
            int l = j & 63; int chunk = j >> 6;
            int nq = chunk & 3, kk = (chunk >> 2) & 3, mt = (chunk >> 4) & 3, sd = chunk >> 6;
            int side = sd >> 2, dd = sd & 3;
            int q = nq * 16 + (l & 15);
            int r = mt * 128 + kk * 32 + (l >> 4) * 8;
            const float* src = (side ? p_xi : p_xj) + (size_t)dd * 32768 + q;
            short8 v;
            #pragma unroll
            for (int e = 0; e < 8; e++) v[e] = f2bf(src[(size_t)(r + e) * 64]);
            *(short8*)(wpt + (size_t)chunk * 512 + l * 8) = v;
        }
    }
}

// ---------------- stats (fallback only) ----------------
__global__ __launch_bounds__(256) void stats_p1(const float* __restrict__ x,
                                                double* __restrict__ part) {
    int blk = blockIdx.x;  // 512
    const float4* X = (const float4*)(x + (size_t)blk * 65536);
    double s = 0.0, sq = 0.0;
    for (int i = threadIdx.x; i < 16384; i += 256) {
        float4 v = X[i];
        s += (double)v.x + (double)v.y + (double)v.z + (double)v.w;
        sq += (double)v.x * v.x + (double)v.y * v.y + (double)v.z * v.z + (double)v.w * v.w;
    }
    __shared__ double rs[256], rq[256];
    rs[threadIdx.x] = s; rq[threadIdx.x] = sq;
    __syncthreads();
    for (int st = 128; st > 0; st >>= 1) {
        if (threadIdx.x < st) { rs[threadIdx.x] += rs[threadIdx.x + st]; rq[threadIdx.x] += rq[threadIdx.x + st]; }
        __syncthreads();
    }
    if (threadIdx.x == 0) { part[blk * 2] = rs[0]; part[blk * 2 + 1] = rq[0]; }
}

__global__ void stats_p2(const double* __restrict__ part, float* __restrict__ stats, int ppb) {
    int b = threadIdx.x;  // 128
    double s = 0.0, sq = 0.0;
    for (int p = 0; p < ppb; p++) { s += part[(b * ppb + p) * 2]; sq += part[(b * ppb + p) * 2 + 1]; }
    double n = 262144.0;
    double mean = s / n;
    double var = (sq - n * mean * mean) / (n - 1.0);
    stats[b * 2 + 0] = (float)(mean * 64.0);
    stats[b * 2 + 1] = (float)(sqrt(var) * 64.0);
}

// ---------------- main MFMA kernel: BK=32, XCD-swizzled, forced 4 waves/SIMD ----------------
// launch_bounds(256,4): 68 arch VGPR + 80 AGPR = 148/thread capped residency at 3
// waves/SIMD (R3-R5). Forcing <=128 total targets 4 blocks/CU (LDS 33.8KB*4 fits).
__global__ __launch_bounds__(256, 4) void main_mfma_kernel(
    const short* __restrict__ xbf, const short* __restrict__ xtbf,
    const short* __restrict__ wcat, const short* __restrict__ wpt,
    float* __restrict__ relsum, float* __restrict__ pt) {
    int blk = blockIdx.x;
    int xcd = blk & 7, rest = blk >> 3;
    int d = rest & 3, side = (rest >> 2) & 1, bhi = rest >> 3;
    int b = bhi * 8 + xcd;            // all 8 blocks of batch b share blk%8 -> same XCD
    const short* Xsw = (side ? xtbf : xbf) + (size_t)b * 262144;
    const short* Wc  = wcat + (size_t)(side * 4 + d) * 65536;
    const short* Wp  = wpt + (size_t)(side * 4 + d) * 32768;

    __shared__ __align__(16) char lds[33792];
    short* Xs  = (short*)lds;              // 8 KB (kt-loop phase)
    short* Wsh = (short*)(lds + 8192);     // 8 KB (kt-loop phase)
    short* Tos = (short*)lds;              // 17408 B overlay (pt phase): 64 x 136 shorts
    short* Wps = (short*)(lds + 17408);    // 16 KB (pt phase)

    int tid = threadIdx.x;
    int w = tid >> 6, l = tid & 63, li = l & 15, lg = l >> 4;
    int wm = w >> 1, wn = w & 1;

    f32x4 zero4 = {0.f, 0.f, 0.f, 0.f};
    f32x4 ptacc[4];
    #pragma unroll
    for (int i = 0; i < 4; i++) ptacc[i] = zero4;
    float esum[4] = {0.f, 0.f, 0.f, 0.f};

    for (int mt = 0; mt < 4; mt++) {
        f32x4 acc[4][4];
        #pragma unroll
        for (int i = 0; i < 4; i++)
            #pragma unroll
            for (int j = 0; j < 4; j++) acc[i][j] = zero4;

        for (int kt = 0; kt < 16; kt++) {
            __syncthreads();
            #pragma unroll
            for (int ii = 0; ii < 4; ii++) {
                int s = w * 4 + ii;
                if (s < 8)
                    gload16(Xsw + ((size_t)((mt * 8 + s) * 16 + kt)) * 512 + l * 8, Xs + s * 512);
                else
                    gload16(Wc + ((size_t)((s - 8) * 16 + kt)) * 512 + l * 8, Wsh + (s - 8) * 512);
            }
            __syncthreads();
            short8 af[4], bfv[4];
            #pragma unroll
            for (int i = 0; i < 4; i++) af[i] = *(const short8*)(Xs + (wm * 4 + i) * 512 + l * 8);
            #pragma unroll
            for (int j = 0; j < 4; j++) bfv[j] = *(const short8*)(Wsh + (wn * 4 + j) * 512 + l * 8);
            #pragma unroll
            for (int i = 0; i < 4; i++)
                #pragma unroll
                for (int j = 0; j < 4; j++)
                    acc[i][j] = __builtin_amdgcn_mfma_f32_16x16x32_bf16(af[i], bfv[j], acc[i][j], 0, 0, 0);
        }

        // prefetch Wp tile for this mt (distinct LDS region, safe to issue now)
        #pragma unroll
        for (int ii = 0; ii < 4; ii++) {
            int s = w * 4 + ii;   // s = kk*4 + nq
            gload16(Wp + ((size_t)((mt * 4 + (s >> 2)) * 4 + (s & 3))) * 512 + l * 8, Wps + s * 512);
        }
        __syncthreads();   // drains Wp loads; all waves done reading Xs/Wsh (Tos overlay safe)

        if (wn == 0) {
            // rel columns: exp colsum accumulation (col = j*16 + li)
            #pragma unroll
            for (int i = 0; i < 4; i++)
                #pragma unroll
                for (int j = 0; j < 4; j++)
                    esum[j] += __expf(acc[i][j][0]) + __expf(acc[i][j][1]) +
                               __expf(acc[i][j][2]) + __expf(acc[i][j][3]);
        } else {
            // o columns: write To^T[p][r_local] (bf16)
            #pragma unroll
            for (int i = 0; i < 4; i++)
                #pragma unroll
                for (int j = 0; j < 4; j++) {
                    int p = j * 16 + li;
                    int rb = wm * 64 + i * 16 + lg * 4;
                    short4v tv;
                    tv.x = f2bf(acc[i][j][0]); tv.y = f2bf(acc[i][j][1]);
                    tv.z = f2bf(acc[i][j][2]); tv.w = f2bf(acc[i][j][3]);
                    *(short4v*)(Tos + p * 136 + rb) = tv;
                }
        }
        __syncthreads();   // Tos visible

        // p_t += To^T @ Wp : wave w owns p rows w*16..w*16+15
        #pragma unroll
        for (int kk = 0; kk < 4; kk++) {
            short8 a = *(const short8*)(Tos + (w * 16 + li) * 136 + kk * 32 + lg * 8);
            #pragma unroll
            for (int nq = 0; nq < 4; nq++) {
                short8 bb = *(const short8*)(Wps + (kk * 4 + nq) * 512 + l * 8);
                ptacc[nq] = __builtin_amdgcn_mfma_f32_16x16x32_bf16(a, bb, ptacc[nq], 0, 0, 0);
            }
        }
    }

    __syncthreads();
    float* red = (float*)lds;
    if (wn == 0) {
        #pragma unroll
        for (int j = 0; j < 4; j++) red[wm * 256 + l * 4 + j] = esum[j];
    }
    __syncthreads();
    size_t base = (size_t)(b * 2 + side) * 4 + d;
    if (tid < 64) {
        float s = 0.f;
        #pragma unroll
        for (int w2 = 0; w2 < 2; w2++)
            #pragma unroll
            for (int g = 0; g < 4; g++)
                s += red[w2 * 256 + (g * 16 + (tid & 15)) * 4 + (tid >> 4)];
        float tot = s;
        #pragma unroll
        for (int off = 1; off < 64; off <<= 1) tot += __shfl_xor(tot, off, 64);
        relsum[base * 64 + tid] = s / tot;
    }
    float* ptout = pt + base * 4096;
    #pragma unroll
    for (int nq = 0; nq < 4; nq++)
        #pragma unroll
        for (int r = 0; r < 4; r++)
            ptout[(size_t)(w * 16 + lg * 4 + r) * 64 + nq * 16 + li] = ptacc[nq][r];
}

// ---------------- fallback fp32 fused kernel (round-1, proven) ----------------
__global__ __launch_bounds__(256) void fused_proj_kernel(
    const float* __restrict__ x,
    const float* __restrict__ o_xj, const float* __restrict__ o_xi,
    const float* __restrict__ p_xj, const float* __restrict__ p_xi,
    const float* __restrict__ o_rel_xj, const float* __restrict__ o_rel_xi,
    float* __restrict__ relsum, float* __restrict__ pt)
{
    int blk = blockIdx.x;
    int b = blk >> 3;
    int side = (blk >> 2) & 1;
    int d = blk & 3;

    const float* Wrel = (side ? o_rel_xi : o_rel_xj) + (size_t)d * (512 * 64);
    const float* Wo   = (side ? o_xi     : o_xj)     + (size_t)d * (512 * 64);
    const float* Wp   = (side ? p_xi     : p_xj)     + (size_t)d * (512 * 64);
    const float* X = x + (size_t)b * (512 * 512);

    __shared__ float Xs[16][68];
    __shared__ float Ws[16][128];
    __shared__ float To[64][68];
    __shared__ float Wps[64][68];
    __shared__ float red[16][64];
    __shared__ float cs[64];
    __shared__ float total_s;

    int tid = threadIdx.x;
    int tx = tid & 15;
    int ty = tid >> 4;

    float paccum[4][4];
    #pragma unroll
    for (int i = 0; i < 4; i++)
        #pragma unroll
        for (int j = 0; j < 4; j++) paccum[i][j] = 0.f;
    float esum[8];
    #pragma unroll
    for (int j = 0; j < 8; j++) esum[j] = 0.f;

    for (int r0 = 0; r0 < 512; r0 += 64) {
        float acc[4][8];
        #pragma unroll
        for (int i = 0; i < 4; i++)
            #pragma unroll
            for (int j = 0; j < 8; j++) acc[i][j] = 0.f;

        for (int k0 = 0; k0 < 512; k0 += 16) {
            if (side == 0) {
                int kk = tid & 15, r = tid >> 4;
                #pragma unroll
                for (int it = 0; it < 4; it++, r += 16)
                    Xs[kk][r] = X[(size_t)(r0 + r) * 512 + (k0 + kk)];
            } else {
                int r = tid & 63, kk = tid >> 6;
                #pragma unroll
                for (int it = 0; it < 4; it++, kk += 4)
                    Xs[kk][r] = X[(size_t)(k0 + kk) * 512 + (r0 + r)];
            }
            {
                int c = tid & 127, kk = tid >> 7;
                const float* Wsrc = (c < 64) ? (Wrel + c) : (Wo + (c - 64));
                #pragma unroll
                for (int it = 0; it < 8; it++, kk += 2)
                    Ws[kk][c] = Wsrc[(size_t)(k0 + kk) * 64];
            }
            __syncthreads();
            #pragma unroll
            for (int kk = 0; kk < 16; kk++) {
                float4 a  = *(const float4*)&Xs[kk][ty * 4];
                float4 b0 = *(const float4*)&Ws[kk][tx * 8];
                float4 b1 = *(const float4*)&Ws[kk][tx * 8 + 4];
                float av[4] = {a.x, a.y, a.z, a.w};
                float bv[8] = {b0.x, b0.y, b0.z, b0.w, b1.x, b1.y, b1.z, b1.w};
                #pragma unroll
                for (int i = 0; i < 4; i++)
                    #pragma unroll
                    for (int j = 0; j < 8; j++)
                        acc[i][j] = fmaf(av[i], bv[j], acc[i][j]);
            }
            __syncthreads();
        }

        if (tx < 8) {
            #pragma unroll
            for (int i = 0; i < 4; i++)
                #pragma unroll
                for (int j = 0; j < 8; j++)
                    esum[j] += expf(acc[i][j]);
        } else {
            #pragma unroll
            for (int i = 0; i < 4; i++) {
                float4 v0 = make_float4(acc[i][0], acc[i][1], acc[i][2], acc[i][3]);
                float4 v1 = make_float4(acc[i][4], acc[i][5], acc[i][6], acc[i][7]);
                *(float4*)&To[ty * 4 + i][(tx - 8) * 8]     = v0;
                *(float4*)&To[ty * 4 + i][(tx - 8) * 8 + 4] = v1;
            }
        }
        {
            int q = tid & 63, r = tid >> 6;
            #pragma unroll
            for (int it = 0; it < 16; it++, r += 4)
                Wps[r][q] = Wp[(size_t)(r0 + r) * 64 + q];
        }
        __syncthreads();
        for (int r = 0; r < 64; r++) {
            float4 aa = *(const float4*)&To[r][ty * 4];
            float4 bb = *(const float4*)&Wps[r][tx * 4];
            float av[4] = {aa.x, aa.y, aa.z, aa.w};
            float bv[4] = {bb.x, bb.y, bb.z, bb.w};
            #pragma unroll
            for (int i = 0; i < 4; i++)
                #pragma unroll
                for (int j = 0; j < 4; j++)
                    paccum[i][j] = fmaf(av[i], bv[j], paccum[i][j]);
        }
        __syncthreads();
    }

    if (tx < 8) {
        #pragma unroll
        for (int j = 0; j < 8; j++) red[ty][tx * 8 + j] = esum[j];
    }
    __syncthreads();
    if (tid < 64) {
        float s = 0.f;
        for (int t = 0; t < 16; t++) s += red[t][tid];
        cs[tid] = s;
    }
    __syncthreads();
    if (tid == 0) {
        float tot = 0.f;
        for (int i = 0; i < 64; i++) tot += cs[i];
        total_s = tot;
    }
    __syncthreads();
    size_t base = (size_t)(b * 2 + side) * 4 + d;
    if (tid < 64) relsum[base * 64 + tid] = cs[tid] / total_s;

    float* ptout = pt + base * 4096;
    #pragma unroll
    for (int i = 0; i < 4; i++)
        #pragma unroll
        for (int j = 0; j < 4; j++)
            ptout[(size_t)(ty * 4 + i) * 64 + tx * 4 + j] = paccum[i][j];
}

// ---------------- finalize per (b,d): stats from partials, atomicAdd into out ----------------
__global__ __launch_bounds__(256) void finalize2_kernel(
    const float* __restrict__ relsum, const float* __restrict__ pt,
    const float* __restrict__ p_rel_xj, const float* __restrict__ p_rel_xi,
    const double* __restrict__ part, const float* __restrict__ stats, int ppb,
    float* __restrict__ out)
{
    int blk = blockIdx.x;
    int b = blk >> 2, d = blk & 3;
    int tid = threadIdx.x, tx = tid & 15, ty = tid >> 4;
    __shared__ float Ptj[64][65], Pti[64][65], Wr[64][65];
    __shared__ float red[16][64];
    __shared__ float fj[64], fi[64];
    __shared__ float rs[256], rq[256];
    __shared__ float bc[1];
    __shared__ float sstat[2];

    if (ppb > 0) {
        if (tid < 64) {
            double s = part[(size_t)(b * 64 + tid) * 2];
            double sq = part[(size_t)(b * 64 + tid) * 2 + 1];
            #pragma unroll
            for (int off = 1; off < 64; off <<= 1) {
                s += __shfl_xor(s, off, 64);
                sq += __shfl_xor(sq, off, 64);
            }
            if (tid == 0) {
                double n = 262144.0;
                double mean = s / n;
                double var = (sq - n * mean * mean) / (n - 1.0);
                sstat[0] = (float)(mean * 64.0);
                sstat[1] = (float)(sqrt(var) * 64.0);
            }
        }
    } else if (tid == 0) {
        sstat[0] = stats[b * 2 + 0];
        sstat[1] = stats[b * 2 + 1];
    }

    const float* ptj = pt + ((size_t)(b * 2 + 0) * 4 + d) * 4096;
    const float* pti = pt + ((size_t)(b * 2 + 1) * 4 + d) * 4096;
    for (int it = 0; it < 16; it++) {
        int idx = tid + it * 256;
        Ptj[idx >> 6][idx & 63] = ptj[idx];
        Pti[idx >> 6][idx & 63] = pti[idx];
    }
    __syncthreads();
    float x_mean = sstat[0];
    float x_std  = sstat[1];

    for (int s = 0; s < 2; s++) {
        const float* prel = (s == 0) ? (p_rel_xj + (size_t)d * 4096)
                                     : (p_rel_xi + (size_t)d * 4096);
        for (int it = 0; it < 16; it++) {
            int idx = tid + it * 256;
            Wr[idx >> 6][idx & 63] = prel[idx];
        }
        __syncthreads();
        float cpart[4] = {0.f, 0.f, 0.f, 0.f};
        for (int i = 0; i < 4; i++) {
            int p = ty * 4 + i;
            float q[4] = {0.f, 0.f, 0.f, 0.f};
            for (int r = 0; r < 64; r++) {
                float a = (s == 0) ? Ptj[p][r] : Pti[p][r];
                #pragma unroll
                for (int j = 0; j < 4; j++)
                    q[j] = fmaf(a, Wr[r][tx * 4 + j], q[j]);
            }
            #pragma unroll
            for (int j = 0; j < 4; j++) cpart[j] += __expf(q[j]);
        }
        #pragma unroll
        for (int j = 0; j < 4; j++) red[ty][tx * 4 + j] = cpart[j];
        __syncthreads();
        float* ftgt = (s == 0) ? fj : fi;
        if (tid < 64) {
            float cssum = 0.f;
            for (int t = 0; t < 16; t++) cssum += red[t][tid];
            ftgt[tid] = cssum;
        }
        __syncthreads();
        if (tid == 0) {
            float tot = 0.f;
            for (int i = 0; i < 64; i++) tot += ftgt[i];
            bc[0] = tot;
        }
        __syncthreads();
        if (tid < 64) {
            float prel_sum = ftgt[tid] / bc[0];
            float orel = relsum[((size_t)(b * 2 + s) * 4 + d) * 64 + tid];
            ftgt[tid] = sqrtf(orel / prel_sum);
        }
        __syncthreads();
    }

    float v[4][4];
    float psum = 0.f, psq = 0.f;
    #pragma unroll
    for (int i = 0; i < 4; i++) {
        int r = ty * 4 + i;
        #pragma unroll
        for (int j = 0; j < 4; j++) {
            int c = tx * 4 + j;
            float val = Ptj[r][c] * fj[r] + Pti[c][r] * fi[c];
            v[i][j] = val; psum += val; psq += val * val;
        }
    }
    rs[tid] = psum; rq[tid] = psq;
    __syncthreads();
    for (int st = 128; st > 0; st >>= 1) {
        if (tid < st) { rs[tid] += rs[tid + st]; rq[tid] += rq[tid + st]; }
        __syncthreads();
    }
    float mean = rs[0] / 4096.f;
    float var = (rq[0] - 4096.f * mean * mean) / 4095.f;
    float inv = 1.0f / (sqrtf(var) + EPSF);
    float* ob = out + (size_t)b * 4096;
    #pragma unroll
    for (int i = 0; i < 4; i++)
        #pragma unroll
        for (int j = 0; j < 4; j++)
            atomicAdd(&ob[(size_t)(ty * 4 + i) * 64 + tx * 4 + j],
                      (v[i][j] - mean) * inv * x_std + x_mean);
}

extern "C" void kernel_launch(void* const* d_in, const int* in_sizes, int n_in,
                              void* d_out, int out_size, void* d_ws, size_t ws_size,
                              hipStream_t stream) {
    const float* x        = (const float*)d_in[0];
    const float* o_xj     = (const float*)d_in[1];
    const float* o_xi     = (const float*)d_in[2];
    const float* p_xj     = (const float*)d_in[3];
    const float* p_xi     = (const float*)d_in[4];
    const float* o_rel_xj = (const float*)d_in[5];
    const float* o_rel_xi = (const float*)d_in[6];
    const float* p_rel_xj = (const float*)d_in[7];
    const float* p_rel_xi = (const float*)d_in[8];
    float* out = (float*)d_out;

    char* ws = (char*)d_ws;
    float*  stats  = (float*)(ws + 0);           // 1024
    float*  relsum = (float*)(ws + 1024);        // 262144
    float*  pt     = (float*)(ws + 263168);      // 16777216
    double* spartF = (double*)(ws + 17040384);   // 131072
    short*  xbf    = (short*)(ws + 17171456);    // 67108864
    short*  xtbf   = (short*)(ws + 84280320);    // 67108864
    short*  wcat   = (short*)(ws + 151389184);   // 1048576
    short*  wptb   = (short*)(ws + 152437760);   // 524288 -> end 152962048
    double* spartS = (double*)(ws + 17040384);   // fallback reuses spartF slot

    hipMemsetAsync(d_out, 0, (size_t)out_size * sizeof(float), stream);

    const size_t FAST_NEED = 152962048;
    if (ws_size >= FAST_NEED) {
        prep_kernel<<<8576, 256, 0, stream>>>(x, o_xj, o_xi, p_xj, p_xi,
                                              o_rel_xj, o_rel_xi,
                                              xbf, xtbf, spartF, wcat, wptb);
        main_mfma_kernel<<<1024, 256, 0, stream>>>(xbf, xtbf, wcat, wptb, relsum, pt);
        finalize2_kernel<<<512, 256, 0, stream>>>(relsum, pt, p_rel_xj, p_rel_xi,
                                                  spartF, stats, 64, out);
    } else {
        if (ws_size >= 17171456) {
            stats_p1<<<512, 256, 0, stream>>>(x, spartS);
            stats_p2<<<1, 128, 0, stream>>>(spartS, stats, 4);
        } else {
            double* sp = (double*)(ws + 263168);
            stats_p1<<<512, 256, 0, stream>>>(x, sp);
            stats_p2<<<1, 128, 0, stream>>>(sp, stats, 4);
        }
        fused_proj_kernel<<<1024, 256, 0, stream>>>(x, o_xj, o_xi, p_xj, p_xi,
                                                    o_rel_xj, o_rel_xi, relsum, pt);
        finalize2_kernel<<<512, 256, 0, stream>>>(relsum, pt, p_rel_xj, p_rel_xi,
                                                  (const double*)nullptr, stats, 0, out);
    }
}

// Round 7
// 343.569 us; speedup vs baseline: 1.2063x; 1.0316x over previous
//
#include <hip/hip_runtime.h>
#include <math.h>

typedef __attribute__((ext_vector_type(8))) short short8;
typedef __attribute__((ext_vector_type(4))) short short4v;
typedef __attribute__((ext_vector_type(4))) float f32x4;

#define EPSF 1e-5f

__device__ __forceinline__ short f2bf(float f) {
    union { float f; unsigned u; } v; v.f = f;
    unsigned r = (v.u + 0x7FFFu + ((v.u >> 16) & 1u)) >> 16;
    return (short)r;
}

__device__ __forceinline__ void gload16(const void* g, void* l) {
    __builtin_amdgcn_global_load_lds(
        (const __attribute__((address_space(1))) unsigned int*)g,
        (__attribute__((address_space(3))) unsigned int*)l, 16, 0, 0);
}

// ---------------- prep: xprep (blocks 0..8191) + wprep (blocks 8192..8575) ----------------
// xbf/xtbf chunk layout (1 KB each): chunk C = (b*32 + R)*16 + kt; element (l*8+e) holds
//   X[R*16 + (l&15)][kt*32 + (l>>4)*8 + e]   (xtbf: same formula on X^T)
// tileR stride = 82 shorts (41 words, odd) -> xtbf column-gather is bank-conflict-free.
__global__ __launch_bounds__(256) void prep_kernel(
    const float* __restrict__ x,
    const float* __restrict__ o_xj, const float* __restrict__ o_xi,
    const float* __restrict__ p_xj, const float* __restrict__ p_xi,
    const float* __restrict__ o_rel_xj, const float* __restrict__ o_rel_xi,
    short* __restrict__ xbf, short* __restrict__ xtbf,
    double* __restrict__ part, short* __restrict__ wcat, short* __restrict__ wpt) {
    int tid = threadIdx.x;
    if (blockIdx.x < 8192) {
        int blk = blockIdx.x;               // 128 b * 64 tiles
        int b = blk >> 6, t = blk & 63;
        int tr = (t >> 3) * 64, tc = (t & 7) * 64;
        const float* X = x + (size_t)b * 262144;
        __shared__ short tileR[64][82];
        __shared__ double rs[256], rq[256];

        {
            int r = tid >> 2, cseg = (tid & 3) * 16;
            const float* src = X + (size_t)(tr + r) * 512 + tc + cseg;
            double s = 0.0, sq = 0.0;
            short vals[16];
            #pragma unroll
            for (int q = 0; q < 4; q++) {
                float4 f = *(const float4*)(src + q * 4);
                vals[q * 4 + 0] = f2bf(f.x); vals[q * 4 + 1] = f2bf(f.y);
                vals[q * 4 + 2] = f2bf(f.z); vals[q * 4 + 3] = f2bf(f.w);
                s += (double)f.x + (double)f.y + (double)f.z + (double)f.w;
                sq += (double)f.x * f.x + (double)f.y * f.y + (double)f.z * f.z + (double)f.w * f.w;
            }
            int* tp = (int*)&tileR[r][cseg];
            #pragma unroll
            for (int q = 0; q < 8; q++) tp[q] = ((const int*)vals)[q];
            rs[tid] = s; rq[tid] = sq;
        }
        __syncthreads();
        for (int st = 128; st > 0; st >>= 1) {
            if (tid < st) { rs[tid] += rs[tid + st]; rq[tid] += rq[tid + st]; }
            __syncthreads();
        }
        if (tid == 0) { part[blk * 2] = rs[0]; part[blk * 2 + 1] = rq[0]; }

        int w = tid >> 6, l = tid & 63, li = l & 15, lg = l >> 4;
        #pragma unroll
        for (int q = 0; q < 2; q++) {
            int cc = w * 2 + q;
            int Rl = cc >> 1, ktl = cc & 1;
            const int* sp = (const int*)&tileR[Rl * 16 + li][ktl * 32 + lg * 8];
            int tmp[4];
            #pragma unroll
            for (int j = 0; j < 4; j++) tmp[j] = sp[j];
            size_t chunk = (size_t)(b * 32 + (tr >> 4) + Rl) * 16 + (tc >> 5) + ktl;
            *(short8*)(xbf + chunk * 512 + l * 8) = *(const short8*)tmp;
        }
        #pragma unroll
        for (int q = 0; q < 2; q++) {
            int cc = w * 2 + q;
            int Rl = cc >> 1, ktl = cc & 1;
            int c_loc = Rl * 16 + li;
            int rbase = ktl * 32 + lg * 8;
            short8 v;
            #pragma unroll
            for (int e = 0; e < 8; e++) v[e] = tileR[rbase + e][c_loc];
            size_t chunk = (size_t)(b * 32 + (tc >> 4) + Rl) * 16 + (tr >> 5) + ktl;
            *(short8*)(xtbf + chunk * 512 + l * 8) = v;
        }
    } else {
        int idx = (blockIdx.x - 8192) * 256 + tid;   // 98304 pieces
        if (idx < 65536) {
            int l = idx & 63; int chunk = idx >> 6;
            int kt = chunk & 15, ns = (chunk >> 4) & 7, sd = chunk >> 7;
            int side = sd >> 2, dd = sd & 3;
            int n = ns * 16 + (l & 15);
            int k = kt * 32 + (l >> 4) * 8;
            const float* src = (n < 64) ? (side ? o_rel_xi : o_rel_xj)
                                        : (side ? o_xi : o_xj);
            src += (size_t)dd * 32768 + (n & 63);
            short8 v;
            #pragma unroll
            for (int e = 0; e < 8; e++) v[e] = f2bf(src[(size_t)(k + e) * 64]);
            *(short8*)(wcat + (size_t)chunk * 512 + l * 8) = v;
        } else {
            int j = idx - 65536;
            int l = j & 63; int chunk = j >> 6;
            int nq = chunk & 3, kk = (chunk >> 2) & 3, mt = (chunk >> 4) & 3, sd = chunk >> 6;
            int side = sd >> 2, dd = sd & 3;
            int q = nq * 16 + (l & 15);
            int r = mt * 128 + kk * 32 + (l >> 4) * 8;
            const float* src = (side ? p_xi : p_xj) + (size_t)dd * 32768 + q;
            short8 v;
            #pragma unroll
            for (int e = 0; e < 8; e++) v[e] = f2bf(src[(size_t)(r + e) * 64]);
            *(short8*)(wpt + (size_t)chunk * 512 + l * 8) = v;
        }
    }
}

// ---------------- stats (fallback only) ----------------
__global__ __launch_bounds__(256) void stats_p1(const float* __restrict__ x,
                                                double* __restrict__ part) {
    int blk = blockIdx.x;  // 512
    const float4* X = (const float4*)(x + (size_t)blk * 65536);
    double s = 0.0, sq = 0.0;
    for (int i = threadIdx.x; i < 16384; i += 256) {
        float4 v = X[i];
        s += (double)v.x + (double)v.y + (double)v.z + (double)v.w;
        sq += (double)v.x * v.x + (double)v.y * v.y + (double)v.z * v.z + (double)v.w * v.w;
    }
    __shared__ double rs[256], rq[256];
    rs[threadIdx.x] = s; rq[threadIdx.x] = sq;
    __syncthreads();
    for (int st = 128; st > 0; st >>= 1) {
        if (threadIdx.x < st) { rs[threadIdx.x] += rs[threadIdx.x + st]; rq[threadIdx.x] += rq[threadIdx.x + st]; }
        __syncthreads();
    }
    if (threadIdx.x == 0) { part[blk * 2] = rs[0]; part[blk * 2 + 1] = rq[0]; }
}

__global__ void stats_p2(const double* __restrict__ part, float* __restrict__ stats, int ppb) {
    int b = threadIdx.x;  // 128
    double s = 0.0, sq = 0.0;
    for (int p = 0; p < ppb; p++) { s += part[(b * ppb + p) * 2]; sq += part[(b * ppb + p) * 2 + 1]; }
    double n = 262144.0;
    double mean = s / n;
    double var = (sq - n * mean * mean) / (n - 1.0);
    stats[b * 2 + 0] = (float)(mean * 64.0);
    stats[b * 2 + 1] = (float)(sqrt(var) * 64.0);
}

// ---------------- main MFMA kernel: BK=32, XCD-swizzled, forced 4 waves/SIMD ----------------
// R6-proven: 84.5 us, MfmaUtil 36.8% (m97-structure plateau). DO NOT TOUCH.
__global__ __launch_bounds__(256, 4) void main_mfma_kernel(
    const short* __restrict__ xbf, const short* __restrict__ xtbf,
    const short* __restrict__ wcat, const short* __restrict__ wpt,
    float* __restrict__ relsum, float* __restrict__ pt) {
    int blk = blockIdx.x;
    int xcd = blk & 7, rest = blk >> 3;
    int d = rest & 3, side = (rest >> 2) & 1, bhi = rest >> 3;
    int b = bhi * 8 + xcd;            // all 8 blocks of batch b share blk%8 -> same XCD
    const short* Xsw = (side ? xtbf : xbf) + (size_t)b * 262144;
    const short* Wc  = wcat + (size_t)(side * 4 + d) * 65536;
    const short* Wp  = wpt + (size_t)(side * 4 + d) * 32768;

    __shared__ __align__(16) char lds[33792];
    short* Xs  = (short*)lds;              // 8 KB (kt-loop phase)
    short* Wsh = (short*)(lds + 8192);     // 8 KB (kt-loop phase)
    short* Tos = (short*)lds;              // 17408 B overlay (pt phase): 64 x 136 shorts
    short* Wps = (short*)(lds + 17408);    // 16 KB (pt phase)

    int tid = threadIdx.x;
    int w = tid >> 6, l = tid & 63, li = l & 15, lg = l >> 4;
    int wm = w >> 1, wn = w & 1;

    f32x4 zero4 = {0.f, 0.f, 0.f, 0.f};
    f32x4 ptacc[4];
    #pragma unroll
    for (int i = 0; i < 4; i++) ptacc[i] = zero4;
    float esum[4] = {0.f, 0.f, 0.f, 0.f};

    for (int mt = 0; mt < 4; mt++) {
        f32x4 acc[4][4];
        #pragma unroll
        for (int i = 0; i < 4; i++)
            #pragma unroll
            for (int j = 0; j < 4; j++) acc[i][j] = zero4;

        for (int kt = 0; kt < 16; kt++) {
            __syncthreads();
            #pragma unroll
            for (int ii = 0; ii < 4; ii++) {
                int s = w * 4 + ii;
                if (s < 8)
                    gload16(Xsw + ((size_t)((mt * 8 + s) * 16 + kt)) * 512 + l * 8, Xs + s * 512);
                else
                    gload16(Wc + ((size_t)((s - 8) * 16 + kt)) * 512 + l * 8, Wsh + (s - 8) * 512);
            }
            __syncthreads();
            short8 af[4], bfv[4];
            #pragma unroll
            for (int i = 0; i < 4; i++) af[i] = *(const short8*)(Xs + (wm * 4 + i) * 512 + l * 8);
            #pragma unroll
            for (int j = 0; j < 4; j++) bfv[j] = *(const short8*)(Wsh + (wn * 4 + j) * 512 + l * 8);
            #pragma unroll
            for (int i = 0; i < 4; i++)
                #pragma unroll
                for (int j = 0; j < 4; j++)
                    acc[i][j] = __builtin_amdgcn_mfma_f32_16x16x32_bf16(af[i], bfv[j], acc[i][j], 0, 0, 0);
        }

        // prefetch Wp tile for this mt (distinct LDS region, safe to issue now)
        #pragma unroll
        for (int ii = 0; ii < 4; ii++) {
            int s = w * 4 + ii;   // s = kk*4 + nq
            gload16(Wp + ((size_t)((mt * 4 + (s >> 2)) * 4 + (s & 3))) * 512 + l * 8, Wps + s * 512);
        }
        __syncthreads();   // drains Wp loads; all waves done reading Xs/Wsh (Tos overlay safe)

        if (wn == 0) {
            // rel columns: exp colsum accumulation (col = j*16 + li)
            #pragma unroll
            for (int i = 0; i < 4; i++)
                #pragma unroll
                for (int j = 0; j < 4; j++)
                    esum[j] += __expf(acc[i][j][0]) + __expf(acc[i][j][1]) +
                               __expf(acc[i][j][2]) + __expf(acc[i][j][3]);
        } else {
            // o columns: write To^T[p][r_local] (bf16)
            #pragma unroll
            for (int i = 0; i < 4; i++)
                #pragma unroll
                for (int j = 0; j < 4; j++) {
                    int p = j * 16 + li;
                    int rb = wm * 64 + i * 16 + lg * 4;
                    short4v tv;
                    tv.x = f2bf(acc[i][j][0]); tv.y = f2bf(acc[i][j][1]);
                    tv.z = f2bf(acc[i][j][2]); tv.w = f2bf(acc[i][j][3]);
                    *(short4v*)(Tos + p * 136 + rb) = tv;
                }
        }
        __syncthreads();   // Tos visible

        // p_t += To^T @ Wp : wave w owns p rows w*16..w*16+15
        #pragma unroll
        for (int kk = 0; kk < 4; kk++) {
            short8 a = *(const short8*)(Tos + (w * 16 + li) * 136 + kk * 32 + lg * 8);
            #pragma unroll
            for (int nq = 0; nq < 4; nq++) {
                short8 bb = *(const short8*)(Wps + (kk * 4 + nq) * 512 + l * 8);
                ptacc[nq] = __builtin_amdgcn_mfma_f32_16x16x32_bf16(a, bb, ptacc[nq], 0, 0, 0);
            }
        }
    }

    __syncthreads();
    float* red = (float*)lds;
    if (wn == 0) {
        #pragma unroll
        for (int j = 0; j < 4; j++) red[wm * 256 + l * 4 + j] = esum[j];
    }
    __syncthreads();
    size_t base = (size_t)(b * 2 + side) * 4 + d;
    if (tid < 64) {
        float s = 0.f;
        #pragma unroll
        for (int w2 = 0; w2 < 2; w2++)
            #pragma unroll
            for (int g = 0; g < 4; g++)
                s += red[w2 * 256 + (g * 16 + (tid & 15)) * 4 + (tid >> 4)];
        float tot = s;
        #pragma unroll
        for (int off = 1; off < 64; off <<= 1) tot += __shfl_xor(tot, off, 64);
        relsum[base * 64 + tid] = s / tot;
    }
    float* ptout = pt + base * 4096;
    #pragma unroll
    for (int nq = 0; nq < 4; nq++)
        #pragma unroll
        for (int r = 0; r < 4; r++)
            ptout[(size_t)(w * 16 + lg * 4 + r) * 64 + nq * 16 + li] = ptacc[nq][r];
}

// ---------------- fallback fp32 fused kernel (round-1, proven) ----------------
__global__ __launch_bounds__(256) void fused_proj_kernel(
    const float* __restrict__ x,
    const float* __restrict__ o_xj, const float* __restrict__ o_xi,
    const float* __restrict__ p_xj, const float* __restrict__ p_xi,
    const float* __restrict__ o_rel_xj, const float* __restrict__ o_rel_xi,
    float* __restrict__ relsum, float* __restrict__ pt)
{
    int blk = blockIdx.x;
    int b = blk >> 3;
    int side = (blk >> 2) & 1;
    int d = blk & 3;

    const float* Wrel = (side ? o_rel_xi : o_rel_xj) + (size_t)d * (512 * 64);
    const float* Wo   = (side ? o_xi     : o_xj)     + (size_t)d * (512 * 64);
    const float* Wp   = (side ? p_xi     : p_xj)     + (size_t)d * (512 * 64);
    const float* X = x + (size_t)b * (512 * 512);

    __shared__ float Xs[16][68];
    __shared__ float Ws[16][128];
    __shared__ float To[64][68];
    __shared__ float Wps[64][68];
    __shared__ float red[16][64];
    __shared__ float cs[64];
    __shared__ float total_s;

    int tid = threadIdx.x;
    int tx = tid & 15;
    int ty = tid >> 4;

    float paccum[4][4];
    #pragma unroll
    for (int i = 0; i < 4; i++)
        #pragma unroll
        for (int j = 0; j < 4; j++) paccum[i][j] = 0.f;
    float esum[8];
    #pragma unroll
    for (int j = 0; j < 8; j++) esum[j] = 0.f;

    for (int r0 = 0; r0 < 512; r0 += 64) {
        float acc[4][8];
        #pragma unroll
        for (int i = 0; i < 4; i++)
            #pragma unroll
            for (int j = 0; j < 8; j++) acc[i][j] = 0.f;

        for (int k0 = 0; k0 < 512; k0 += 16) {
            if (side == 0) {
                int kk = tid & 15, r = tid >> 4;
                #pragma unroll
                for (int it = 0; it < 4; it++, r += 16)
                    Xs[kk][r] = X[(size_t)(r0 + r) * 512 + (k0 + kk)];
            } else {
                int r = tid & 63, kk = tid >> 6;
                #pragma unroll
                for (int it = 0; it < 4; it++, kk += 4)
                    Xs[kk][r] = X[(size_t)(k0 + kk) * 512 + (r0 + r)];
            }
            {
                int c = tid & 127, kk = tid >> 7;
                const float* Wsrc = (c < 64) ? (Wrel + c) : (Wo + (c - 64));
                #pragma unroll
                for (int it = 0; it < 8; it++, kk += 2)
                    Ws[kk][c] = Wsrc[(size_t)(k0 + kk) * 64];
            }
            __syncthreads();
            #pragma unroll
            for (int kk = 0; kk < 16; kk++) {
                float4 a  = *(const float4*)&Xs[kk][ty * 4];
                float4 b0 = *(const float4*)&Ws[kk][tx * 8];
                float4 b1 = *(const float4*)&Ws[kk][tx * 8 + 4];
                float av[4] = {a.x, a.y, a.z, a.w};
                float bv[8] = {b0.x, b0.y, b0.z, b0.w, b1.x, b1.y, b1.z, b1.w};
                #pragma unroll
                for (int i = 0; i < 4; i++)
                    #pragma unroll
                    for (int j = 0; j < 8; j++)
                        acc[i][j] = fmaf(av[i], bv[j], acc[i][j]);
            }
            __syncthreads();
        }

        if (tx < 8) {
            #pragma unroll
            for (int i = 0; i < 4; i++)
                #pragma unroll
                for (int j = 0; j < 8; j++)
                    esum[j] += expf(acc[i][j]);
        } else {
            #pragma unroll
            for (int i = 0; i < 4; i++) {
                float4 v0 = make_float4(acc[i][0], acc[i][1], acc[i][2], acc[i][3]);
                float4 v1 = make_float4(acc[i][4], acc[i][5], acc[i][6], acc[i][7]);
                *(float4*)&To[ty * 4 + i][(tx - 8) * 8]     = v0;
                *(float4*)&To[ty * 4 + i][(tx - 8) * 8 + 4] = v1;
            }
        }
        {
            int q = tid & 63, r = tid >> 6;
            #pragma unroll
            for (int it = 0; it < 16; it++, r += 4)
                Wps[r][q] = Wp[(size_t)(r0 + r) * 64 + q];
        }
        __syncthreads();
        for (int r = 0; r < 64; r++) {
            float4 aa = *(const float4*)&To[r][ty * 4];
            float4 bb = *(const float4*)&Wps[r][tx * 4];
            float av[4] = {aa.x, aa.y, aa.z, aa.w};
            float bv[4] = {bb.x, bb.y, bb.z, bb.w};
            #pragma unroll
            for (int i = 0; i < 4; i++)
                #pragma unroll
                for (int j = 0; j < 4; j++)
                    paccum[i][j] = fmaf(av[i], bv[j], paccum[i][j]);
        }
        __syncthreads();
    }

    if (tx < 8) {
        #pragma unroll
        for (int j = 0; j < 8; j++) red[ty][tx * 8 + j] = esum[j];
    }
    __syncthreads();
    if (tid < 64) {
        float s = 0.f;
        for (int t = 0; t < 16; t++) s += red[t][tid];
        cs[tid] = s;
    }
    __syncthreads();
    if (tid == 0) {
        float tot = 0.f;
        for (int i = 0; i < 64; i++) tot += cs[i];
        total_s = tot;
    }
    __syncthreads();
    size_t base = (size_t)(b * 2 + side) * 4 + d;
    if (tid < 64) relsum[base * 64 + tid] = cs[tid] / total_s;

    float* ptout = pt + base * 4096;
    #pragma unroll
    for (int i = 0; i < 4; i++)
        #pragma unroll
        for (int j = 0; j < 4; j++)
            ptout[(size_t)(ty * 4 + i) * 64 + tx * 4 + j] = paccum[i][j];
}

// ---------------- finalize per (b,d): vectorized LDS matmuls, atomicAdd into out ----------------
// Row stride 68 floats (272 B, 16-B aligned) so Wr rows support ds_read_b128;
// Wr float4 read = 2-way bank (free), Pt scalar read = broadcast within ty-group.
__global__ __launch_bounds__(256) void finalize2_kernel(
    const float* __restrict__ relsum, const float* __restrict__ pt,
    const float* __restrict__ p_rel_xj, const float* __restrict__ p_rel_xi,
    const double* __restrict__ part, const float* __restrict__ stats, int ppb,
    float* __restrict__ out)
{
    int blk = blockIdx.x;
    int b = blk >> 2, d = blk & 3;
    int tid = threadIdx.x, tx = tid & 15, ty = tid >> 4;
    __shared__ __align__(16) float Ptj[64][68], Pti[64][68], Wr[64][68];
    __shared__ float red[16][64];
    __shared__ float fj[64], fi[64];
    __shared__ float rs[256], rq[256];
    __shared__ float bc[1];
    __shared__ float sstat[2];

    if (ppb > 0) {
        if (tid < 64) {
            double s = part[(size_t)(b * 64 + tid) * 2];
            double sq = part[(size_t)(b * 64 + tid) * 2 + 1];
            #pragma unroll
            for (int off = 1; off < 64; off <<= 1) {
                s += __shfl_xor(s, off, 64);
                sq += __shfl_xor(sq, off, 64);
            }
            if (tid == 0) {
                double n = 262144.0;
                double mean = s / n;
                double var = (sq - n * mean * mean) / (n - 1.0);
                sstat[0] = (float)(mean * 64.0);
                sstat[1] = (float)(sqrt(var) * 64.0);
            }
        }
    } else if (tid == 0) {
        sstat[0] = stats[b * 2 + 0];
        sstat[1] = stats[b * 2 + 1];
    }

    const float* ptj = pt + ((size_t)(b * 2 + 0) * 4 + d) * 4096;
    const float* pti = pt + ((size_t)(b * 2 + 1) * 4 + d) * 4096;
    for (int it = 0; it < 16; it++) {
        int idx = tid + it * 256;
        Ptj[idx >> 6][idx & 63] = ptj[idx];
        Pti[idx >> 6][idx & 63] = pti[idx];
    }
    __syncthreads();
    float x_mean = sstat[0];
    float x_std  = sstat[1];

    for (int s = 0; s < 2; s++) {
        const float* prel = (s == 0) ? (p_rel_xj + (size_t)d * 4096)
                                     : (p_rel_xi + (size_t)d * 4096);
        for (int it = 0; it < 16; it++) {
            int idx = tid + it * 256;
            Wr[idx >> 6][idx & 63] = prel[idx];
        }
        __syncthreads();
        const float (*Pt)[68] = (s == 0) ? Ptj : Pti;
        // q[i][j] = sum_r Pt[ty*4+i][r] * Wr[r][tx*4+j]
        float q[4][4];
        #pragma unroll
        for (int i = 0; i < 4; i++)
            #pragma unroll
            for (int j = 0; j < 4; j++) q[i][j] = 0.f;
        for (int r = 0; r < 64; r++) {
            float4 bv = *(const float4*)&Wr[r][tx * 4];
            #pragma unroll
            for (int i = 0; i < 4; i++) {
                float a = Pt[ty * 4 + i][r];
                q[i][0] = fmaf(a, bv.x, q[i][0]);
                q[i][1] = fmaf(a, bv.y, q[i][1]);
                q[i][2] = fmaf(a, bv.z, q[i][2]);
                q[i][3] = fmaf(a, bv.w, q[i][3]);
            }
        }
        float cpart[4];
        #pragma unroll
        for (int j = 0; j < 4; j++)
            cpart[j] = __expf(q[0][j]) + __expf(q[1][j]) + __expf(q[2][j]) + __expf(q[3][j]);
        #pragma unroll
        for (int j = 0; j < 4; j++) red[ty][tx * 4 + j] = cpart[j];
        __syncthreads();
        float* ftgt = (s == 0) ? fj : fi;
        if (tid < 64) {
            float cssum = 0.f;
            for (int t = 0; t < 16; t++) cssum += red[t][tid];
            ftgt[tid] = cssum;
        }
        __syncthreads();
        if (tid == 0) {
            float tot = 0.f;
            for (int i = 0; i < 64; i++) tot += ftgt[i];
            bc[0] = tot;
        }
        __syncthreads();
        if (tid < 64) {
            float prel_sum = ftgt[tid] / bc[0];
            float orel = relsum[((size_t)(b * 2 + s) * 4 + d) * 64 + tid];
            ftgt[tid] = sqrtf(orel / prel_sum);
        }
        __syncthreads();
    }

    float v[4][4];
    float psum = 0.f, psq = 0.f;
    #pragma unroll
    for (int i = 0; i < 4; i++) {
        int r = ty * 4 + i;
        #pragma unroll
        for (int j = 0; j < 4; j++) {
            int c = tx * 4 + j;
            float val = Ptj[r][c] * fj[r] + Pti[c][r] * fi[c];
            v[i][j] = val; psum += val; psq += val * val;
        }
    }
    rs[tid] = psum; rq[tid] = psq;
    __syncthreads();
    for (int st = 128; st > 0; st >>= 1) {
        if (tid < st) { rs[tid] += rs[tid + st]; rq[tid] += rq[tid + st]; }
        __syncthreads();
    }
    float mean = rs[0] / 4096.f;
    float var = (rq[0] - 4096.f * mean * mean) / 4095.f;
    float inv = 1.0f / (sqrtf(var) + EPSF);
    float* ob = out + (size_t)b * 4096;
    #pragma unroll
    for (int i = 0; i < 4; i++)
        #pragma unroll
        for (int j = 0; j < 4; j++)
            atomicAdd(&ob[(size_t)(ty * 4 + i) * 64 + tx * 4 + j],
                      (v[i][j] - mean) * inv * x_std + x_mean);
}

extern "C" void kernel_launch(void* const* d_in, const int* in_sizes, int n_in,
                              void* d_out, int out_size, void* d_ws, size_t ws_size,
                              hipStream_t stream) {
    const float* x        = (const float*)d_in[0];
    const float* o_xj     = (const float*)d_in[1];
    const float* o_xi     = (const float*)d_in[2];
    const float* p_xj     = (const float*)d_in[3];
    const float* p_xi     = (const float*)d_in[4];
    const float* o_rel_xj = (const float*)d_in[5];
    const float* o_rel_xi = (const float*)d_in[6];
    const float* p_rel_xj = (const float*)d_in[7];
    const float* p_rel_xi = (const float*)d_in[8];
    float* out = (float*)d_out;

    char* ws = (char*)d_ws;
    float*  stats  = (float*)(ws + 0);           // 1024
    float*  relsum = (float*)(ws + 1024);        // 262144
    float*  pt     = (float*)(ws + 263168);      // 16777216
    double* spartF = (double*)(ws + 17040384);   // 131072
    short*  xbf    = (short*)(ws + 17171456);    // 67108864
    short*  xtbf   = (short*)(ws + 84280320);    // 67108864
    short*  wcat   = (short*)(ws + 151389184);   // 1048576
    short*  wptb   = (short*)(ws + 152437760);   // 524288 -> end 152962048
    double* spartS = (double*)(ws + 17040384);   // fallback reuses spartF slot

    hipMemsetAsync(d_out, 0, (size_t)out_size * sizeof(float), stream);

    const size_t FAST_NEED = 152962048;
    if (ws_size >= FAST_NEED) {
        prep_kernel<<<8576, 256, 0, stream>>>(x, o_xj, o_xi, p_xj, p_xi,
                                              o_rel_xj, o_rel_xi,
                                              xbf, xtbf, spartF, wcat, wptb);
        main_mfma_kernel<<<1024, 256, 0, stream>>>(xbf, xtbf, wcat, wptb, relsum, pt);
        finalize2_kernel<<<512, 256, 0, stream>>>(relsum, pt, p_rel_xj, p_rel_xi,
                                                  spartF, stats, 64, out);
    } else {
        if (ws_size >= 17171456) {
            stats_p1<<<512, 256, 0, stream>>>(x, spartS);
            stats_p2<<<1, 128, 0, stream>>>(spartS, stats, 4);
        } else {
            double* sp = (double*)(ws + 263168);
            stats_p1<<<512, 256, 0, stream>>>(x, sp);
            stats_p2<<<1, 128, 0, stream>>>(sp, stats, 4);
        }
        fused_proj_kernel<<<1024, 256, 0, stream>>>(x, o_xj, o_xi, p_xj, p_xi,
                                                    o_rel_xj, o_rel_xi, relsum, pt);
        finalize2_kernel<<<512, 256, 0, stream>>>(relsum, pt, p_rel_xj, p_rel_xi,
                                                  (const double*)nullptr, stats, 0, out);
    }
}

// Round 9
// 338.889 us; speedup vs baseline: 1.2230x; 1.0138x over previous
//
#include <hip/hip_runtime.h>
#include <math.h>

typedef __attribute__((ext_vector_type(8))) short short8;
typedef __attribute__((ext_vector_type(4))) short short4v;
typedef __attribute__((ext_vector_type(4))) float f32x4;

#define EPSF 1e-5f

__device__ __forceinline__ short f2bf(float f) {
    union { float f; unsigned u; } v; v.f = f;
    unsigned r = (v.u + 0x7FFFu + ((v.u >> 16) & 1u)) >> 16;
    return (short)r;
}

__device__ __forceinline__ void gload16(const void* g, void* l) {
    __builtin_amdgcn_global_load_lds(
        (const __attribute__((address_space(1))) unsigned int*)g,
        (__attribute__((address_space(3))) unsigned int*)l, 16, 0, 0);
}

// ---------------- prep: xprep (blocks 0..4095) + wprep (blocks 4096..4479) ----------------
// xbf/xtbf chunk layout (1 KB each): chunk C = (b*32 + R)*16 + kt; element (l*8+e) holds
//   X[R*16 + (l&15)][kt*32 + (l>>4)*8 + e]   (xtbf: same formula on X^T)
// xprep block = 16 rows x 512 cols of x (contiguous 32 KB): gload16 linear staging
// (NOTE: global addr must be per-lane, + l*4 floats — R8 bug was wave-uniform addr),
// vectorized b128 xbf gather, bank-clean b32 transposed xtbf gather, shuffle stats.
__global__ __launch_bounds__(256) void prep_kernel(
    const float* __restrict__ x,
    const float* __restrict__ o_xj, const float* __restrict__ o_xi,
    const float* __restrict__ p_xj, const float* __restrict__ p_xi,
    const float* __restrict__ o_rel_xj, const float* __restrict__ o_rel_xi,
    short* __restrict__ xbf, short* __restrict__ xtbf,
    double* __restrict__ part, short* __restrict__ wcat, short* __restrict__ wpt) {
    int tid = threadIdx.x;
    if (blockIdx.x < 4096) {
        int blk = blockIdx.x;               // 128 b * 32 R-slabs
        int b = blk >> 5, R = blk & 31;
        const float* X = x + (size_t)b * 262144 + (size_t)R * 16 * 512;
        __shared__ __align__(16) float tile[16 * 512];   // 32 KB, verbatim x slab
        __shared__ double wsum[4][2];
        int w = tid >> 6, l = tid & 63, li = l & 15, lg = l >> 4;

        // stage: linear copy, 8 x 1KB per wave; lane l loads floats [s*256+l*4, +4)
        #pragma unroll
        for (int ii = 0; ii < 8; ii++) {
            int s = w * 8 + ii;             // 0..31
            gload16(X + s * 256 + l * 4, tile + s * 256);
        }
        __syncthreads();                    // drains vmcnt

        // xbf: 4 chunks per thread-wave-slot; stats from these reads (full coverage)
        double s = 0.0, sq = 0.0;
        #pragma unroll
        for (int q = 0; q < 4; q++) {
            int kt = w * 4 + q;
            const float* p0 = tile + li * 512 + kt * 32 + lg * 8;
            float4 f0 = *(const float4*)p0;
            float4 f1 = *(const float4*)(p0 + 4);
            short v[8];
            v[0] = f2bf(f0.x); v[1] = f2bf(f0.y); v[2] = f2bf(f0.z); v[3] = f2bf(f0.w);
            v[4] = f2bf(f1.x); v[5] = f2bf(f1.y); v[6] = f2bf(f1.z); v[7] = f2bf(f1.w);
            s += (double)f0.x + (double)f0.y + (double)f0.z + (double)f0.w
               + (double)f1.x + (double)f1.y + (double)f1.z + (double)f1.w;
            sq += (double)f0.x * f0.x + (double)f0.y * f0.y + (double)f0.z * f0.z + (double)f0.w * f0.w
                + (double)f1.x * f1.x + (double)f1.y * f1.y + (double)f1.z * f1.z + (double)f1.w * f1.w;
            size_t chunk = (size_t)((b * 32 + R) * 16 + kt);
            *(short8*)(xbf + chunk * 512 + l * 8) = *(const short8*)v;
        }

        // xtbf: 4 half-chunk pieces per thread (2 half-chunks per wave per q)
        int base_lg = (R & 1) * 2;
        int kt2 = R >> 1;
        int lh = l & 31, li2 = lh & 15, lgo = lh >> 4;
        #pragma unroll
        for (int q = 0; q < 4; q++) {
            int p = w * 8 + q * 2 + (l >> 5);   // R' = 0..31
            short v[8];
            #pragma unroll
            for (int e = 0; e < 8; e++)
                v[e] = f2bf(tile[(lgo * 8 + e) * 512 + p * 16 + li2]);
            size_t chunk = (size_t)((b * 32 + p) * 16 + kt2);
            *(short8*)(xtbf + chunk * 512 + (base_lg + lgo) * 128 + li2 * 8) = *(const short8*)v;
        }

        // stats: wave shuffle reduce + tiny cross-wave hop
        #pragma unroll
        for (int off = 1; off < 64; off <<= 1) {
            s += __shfl_xor(s, off, 64);
            sq += __shfl_xor(sq, off, 64);
        }
        if (l == 0) { wsum[w][0] = s; wsum[w][1] = sq; }
        __syncthreads();
        if (tid == 0) {
            double ts = wsum[0][0] + wsum[1][0] + wsum[2][0] + wsum[3][0];
            double tq = wsum[0][1] + wsum[1][1] + wsum[2][1] + wsum[3][1];
            part[blk * 2] = ts; part[blk * 2 + 1] = tq;
        }
    } else {
        int idx = (blockIdx.x - 4096) * 256 + tid;   // 98304 pieces
        if (idx < 65536) {
            int l = idx & 63; int chunk = idx >> 6;
            int kt = chunk & 15, ns = (chunk >> 4) & 7, sd = chunk >> 7;
            int side = sd >> 2, dd = sd & 3;
            int n = ns * 16 + (l & 15);
            int k = kt * 32 + (l >> 4) * 8;
            const float* src = (n < 64) ? (side ? o_rel_xi : o_rel_xj)
                                        : (side ? o_xi : o_xj);
            src += (size_t)dd * 32768 + (n & 63);
            short8 v;
            #pragma unroll
            for (int e = 0; e < 8; e++) v[e] = f2bf(src[(size_t)(k + e) * 64]);
            *(short8*)(wcat + (size_t)chunk * 512 + l * 8) = v;
        } else {
            int j = idx - 65536;
            int l = j & 63; int chunk = j >> 6;
            int nq = chunk & 3, kk = (chunk >> 2) & 3, mt = (chunk >> 4) & 3, sd = chunk >> 6;
            int side = sd >> 2, dd = sd & 3;
            int q = nq * 16 + (l & 15);
            int r = mt * 128 + kk * 32 + (l >> 4) * 8;
            const float* src = (side ? p_xi : p_xj) + (size_t)dd * 32768 + q;
            short8 v;
            #pragma unroll
            for (int e = 0; e < 8; e++) v[e] = f2bf(src[(size_t)(r + e) * 64]);
            *(short8*)(wpt + (size_t)chunk * 512 + l * 8) = v;
        }
    }
}

// ---------------- stats (fallback only) ----------------
__global__ __launch_bounds__(256) void stats_p1(const float* __restrict__ x,
                                                double* __restrict__ part) {
    int blk = blockIdx.x;  // 512
    const float4* X = (const float4*)(x + (size_t)blk * 65536);
    double s = 0.0, sq = 0.0;
    for (int i = threadIdx.x; i < 16384; i += 256) {
        float4 v = X[i];
        s += (double)v.x + (double)v.y + (double)v.z + (double)v.w;
        sq += (double)v.x * v.x + (double)v.y * v.y + (double)v.z * v.z + (double)v.w * v.w;
    }
    __shared__ double rs[256], rq[256];
    rs[threadIdx.x] = s; rq[threadIdx.x] = sq;
    __syncthreads();
    for (int st = 128; st > 0; st >>= 1) {
        if (threadIdx.x < st) { rs[threadIdx.x] += rs[threadIdx.x + st]; rq[threadIdx.x] += rq[threadIdx.x + st]; }
        __syncthreads();
    }
    if (threadIdx.x == 0) { part[blk * 2] = rs[0]; part[blk * 2 + 1] = rq[0]; }
}

__global__ void stats_p2(const double* __restrict__ part, float* __restrict__ stats, int ppb) {
    int b = threadIdx.x;  // 128
    double s = 0.0, sq = 0.0;
    for (int p = 0; p < ppb; p++) { s += part[(b * ppb + p) * 2]; sq += part[(b * ppb + p) * 2 + 1]; }
    double n = 262144.0;
    double mean = s / n;
    double var = (sq - n * mean * mean) / (n - 1.0);
    stats[b * 2 + 0] = (float)(mean * 64.0);
    stats[b * 2 + 1] = (float)(sqrt(var) * 64.0);
}

// ---------------- main MFMA kernel: BK=32, XCD-swizzled, forced 4 waves/SIMD ----------------
// R6-proven: 84.5 us, MfmaUtil 36.8% (m97-structure plateau). DO NOT TOUCH.
__global__ __launch_bounds__(256, 4) void main_mfma_kernel(
    const short* __restrict__ xbf, const short* __restrict__ xtbf,
    const short* __restrict__ wcat, const short* __restrict__ wpt,
    float* __restrict__ relsum, float* __restrict__ pt) {
    int blk = blockIdx.x;
    int xcd = blk & 7, rest = blk >> 3;
    int d = rest & 3, side = (rest >> 2) & 1, bhi = rest >> 3;
    int b = bhi * 8 + xcd;            // all 8 blocks of batch b share blk%8 -> same XCD
    const short* Xsw = (side ? xtbf : xbf) + (size_t)b * 262144;
    const short* Wc  = wcat + (size_t)(side * 4 + d) * 65536;
    const short* Wp  = wpt + (size_t)(side * 4 + d) * 32768;

    __shared__ __align__(16) char lds[33792];
    short* Xs  = (short*)lds;              // 8 KB (kt-loop phase)
    short* Wsh = (short*)(lds + 8192);     // 8 KB (kt-loop phase)
    short* Tos = (short*)lds;              // 17408 B overlay (pt phase): 64 x 136 shorts
    short* Wps = (short*)(lds + 17408);    // 16 KB (pt phase)

    int tid = threadIdx.x;
    int w = tid >> 6, l = tid & 63, li = l & 15, lg = l >> 4;
    int wm = w >> 1, wn = w & 1;

    f32x4 zero4 = {0.f, 0.f, 0.f, 0.f};
    f32x4 ptacc[4];
    #pragma unroll
    for (int i = 0; i < 4; i++) ptacc[i] = zero4;
    float esum[4] = {0.f, 0.f, 0.f, 0.f};

    for (int mt = 0; mt < 4; mt++) {
        f32x4 acc[4][4];
        #pragma unroll
        for (int i = 0; i < 4; i++)
            #pragma unroll
            for (int j = 0; j < 4; j++) acc[i][j] = zero4;

        for (int kt = 0; kt < 16; kt++) {
            __syncthreads();
            #pragma unroll
            for (int ii = 0; ii < 4; ii++) {
                int s = w * 4 + ii;
                if (s < 8)
                    gload16(Xsw + ((size_t)((mt * 8 + s) * 16 + kt)) * 512 + l * 8, Xs + s * 512);
                else
                    gload16(Wc + ((size_t)((s - 8) * 16 + kt)) * 512 + l * 8, Wsh + (s - 8) * 512);
            }
            __syncthreads();
            short8 af[4], bfv[4];
            #pragma unroll
            for (int i = 0; i < 4; i++) af[i] = *(const short8*)(Xs + (wm * 4 + i) * 512 + l * 8);
            #pragma unroll
            for (int j = 0; j < 4; j++) bfv[j] = *(const short8*)(Wsh + (wn * 4 + j) * 512 + l * 8);
            #pragma unroll
            for (int i = 0; i < 4; i++)
                #pragma unroll
                for (int j = 0; j < 4; j++)
                    acc[i][j] = __builtin_amdgcn_mfma_f32_16x16x32_bf16(af[i], bfv[j], acc[i][j], 0, 0, 0);
        }

        // prefetch Wp tile for this mt (distinct LDS region, safe to issue now)
        #pragma unroll
        for (int ii = 0; ii < 4; ii++) {
            int s = w * 4 + ii;   // s = kk*4 + nq
            gload16(Wp + ((size_t)((mt * 4 + (s >> 2)) * 4 + (s & 3))) * 512 + l * 8, Wps + s * 512);
        }
        __syncthreads();   // drains Wp loads; all waves done reading Xs/Wsh (Tos overlay safe)

        if (wn == 0) {
            // rel columns: exp colsum accumulation (col = j*16 + li)
            #pragma unroll
            for (int i = 0; i < 4; i++)
                #pragma unroll
                for (int j = 0; j < 4; j++)
                    esum[j] += __expf(acc[i][j][0]) + __expf(acc[i][j][1]) +
                               __expf(acc[i][j][2]) + __expf(acc[i][j][3]);
        } else {
            // o columns: write To^T[p][r_local] (bf16)
            #pragma unroll
            for (int i = 0; i < 4; i++)
                #pragma unroll
                for (int j = 0; j < 4; j++) {
                    int p = j * 16 + li;
                    int rb = wm * 64 + i * 16 + lg * 4;
                    short4v tv;
                    tv.x = f2bf(acc[i][j][0]); tv.y = f2bf(acc[i][j][1]);
                    tv.z = f2bf(acc[i][j][2]); tv.w = f2bf(acc[i][j][3]);
                    *(short4v*)(Tos + p * 136 + rb) = tv;
                }
        }
        __syncthreads();   // Tos visible

        // p_t += To^T @ Wp : wave w owns p rows w*16..w*16+15
        #pragma unroll
        for (int kk = 0; kk < 4; kk++) {
            short8 a = *(const short8*)(Tos + (w * 16 + li) * 136 + kk * 32 + lg * 8);
            #pragma unroll
            for (int nq = 0; nq < 4; nq++) {
                short8 bb = *(const short8*)(Wps + (kk * 4 + nq) * 512 + l * 8);
                ptacc[nq] = __builtin_amdgcn_mfma_f32_16x16x32_bf16(a, bb, ptacc[nq], 0, 0, 0);
            }
        }
    }

    __syncthreads();
    float* red = (float*)lds;
    if (wn == 0) {
        #pragma unroll
        for (int j = 0; j < 4; j++) red[wm * 256 + l * 4 + j] = esum[j];
    }
    __syncthreads();
    size_t base = (size_t)(b * 2 + side) * 4 + d;
    if (tid < 64) {
        float s = 0.f;
        #pragma unroll
        for (int w2 = 0; w2 < 2; w2++)
            #pragma unroll
            for (int g = 0; g < 4; g++)
                s += red[w2 * 256 + (g * 16 + (tid & 15)) * 4 + (tid >> 4)];
        float tot = s;
        #pragma unroll
        for (int off = 1; off < 64; off <<= 1) tot += __shfl_xor(tot, off, 64);
        relsum[base * 64 + tid] = s / tot;
    }
    float* ptout = pt + base * 4096;
    #pragma unroll
    for (int nq = 0; nq < 4; nq++)
        #pragma unroll
        for (int r = 0; r < 4; r++)
            ptout[(size_t)(w * 16 + lg * 4 + r) * 64 + nq * 16 + li] = ptacc[nq][r];
}

// ---------------- fallback fp32 fused kernel (round-1, proven) ----------------
__global__ __launch_bounds__(256) void fused_proj_kernel(
    const float* __restrict__ x,
    const float* __restrict__ o_xj, const float* __restrict__ o_xi,
    const float* __restrict__ p_xj, const float* __restrict__ p_xi,
    const float* __restrict__ o_rel_xj, const float* __restrict__ o_rel_xi,
    float* __restrict__ relsum, float* __restrict__ pt)
{
    int blk = blockIdx.x;
    int b = blk >> 3;
    int side = (blk >> 2) & 1;
    int d = blk & 3;

    const float* Wrel = (side ? o_rel_xi : o_rel_xj) + (size_t)d * (512 * 64);
    const float* Wo   = (side ? o_xi     : o_xj)     + (size_t)d * (512 * 64);
    const float* Wp   = (side ? p_xi     : p_xj)     + (size_t)d * (512 * 64);
    const float* X = x + (size_t)b * (512 * 512);

    __shared__ float Xs[16][68];
    __shared__ float Ws[16][128];
    __shared__ float To[64][68];
    __shared__ float Wps[64][68];
    __shared__ float red[16][64];
    __shared__ float cs[64];
    __shared__ float total_s;

    int tid = threadIdx.x;
    int tx = tid & 15;
    int ty = tid >> 4;

    float paccum[4][4];
    #pragma unroll
    for (int i = 0; i < 4; i++)
        #pragma unroll
        for (int j = 0; j < 4; j++) paccum[i][j] = 0.f;
    float esum[8];
    #pragma unroll
    for (int j = 0; j < 8; j++) esum[j] = 0.f;

    for (int r0 = 0; r0 < 512; r0 += 64) {
        float acc[4][8];
        #pragma unroll
        for (int i = 0; i < 4; i++)
            #pragma unroll
            for (int j = 0; j < 8; j++) acc[i][j] = 0.f;

        for (int k0 = 0; k0 < 512; k0 += 16) {
            if (side == 0) {
                int kk = tid & 15, r = tid >> 4;
                #pragma unroll
                for (int it = 0; it < 4; it++, r += 16)
                    Xs[kk][r] = X[(size_t)(r0 + r) * 512 + (k0 + kk)];
            } else {
                int r = tid & 63, kk = tid >> 6;
                #pragma unroll
                for (int it = 0; it < 4; it++, kk += 4)
                    Xs[kk][r] = X[(size_t)(k0 + kk) * 512 + (r0 + r)];
            }
            {
                int c = tid & 127, kk = tid >> 7;
                const float* Wsrc = (c < 64) ? (Wrel + c) : (Wo + (c - 64));
                #pragma unroll
                for (int it = 0; it < 8; it++, kk += 2)
                    Ws[kk][c] = Wsrc[(size_t)(k0 + kk) * 64];
            }
            __syncthreads();
            #pragma unroll
            for (int kk = 0; kk < 16; kk++) {
                float4 a  = *(const float4*)&Xs[kk][ty * 4];
                float4 b0 = *(const float4*)&Ws[kk][tx * 8];
                float4 b1 = *(const float4*)&Ws[kk][tx * 8 + 4];
                float av[4] = {a.x, a.y, a.z, a.w};
                float bv[8] = {b0.x, b0.y, b0.z, b0.w, b1.x, b1.y, b1.z, b1.w};
                #pragma unroll
                for (int i = 0; i < 4; i++)
                    #pragma unroll
                    for (int j = 0; j < 8; j++)
                        acc[i][j] = fmaf(av[i], bv[j], acc[i][j]);
            }
            __syncthreads();
        }

        if (tx < 8) {
            #pragma unroll
            for (int i = 0; i < 4; i++)
                #pragma unroll
                for (int j = 0; j < 8; j++)
                    esum[j] += expf(acc[i][j]);
        } else {
            #pragma unroll
            for (int i = 0; i < 4; i++) {
                float4 v0 = make_float4(acc[i][0], acc[i][1], acc[i][2], acc[i][3]);
                float4 v1 = make_float4(acc[i][4], acc[i][5], acc[i][6], acc[i][7]);
                *(float4*)&To[ty * 4 + i][(tx - 8) * 8]     = v0;
                *(float4*)&To[ty * 4 + i][(tx - 8) * 8 + 4] = v1;
            }
        }
        {
            int q = tid & 63, r = tid >> 6;
            #pragma unroll
            for (int it = 0; it < 16; it++, r += 4)
                Wps[r][q] = Wp[(size_t)(r0 + r) * 64 + q];
        }
        __syncthreads();
        for (int r = 0; r < 64; r++) {
            float4 aa = *(const float4*)&To[r][ty * 4];
            float4 bb = *(const float4*)&Wps[r][tx * 4];
            float av[4] = {aa.x, aa.y, aa.z, aa.w};
            float bv[4] = {bb.x, bb.y, bb.z, bb.w};
            #pragma unroll
            for (int i = 0; i < 4; i++)
                #pragma unroll
                for (int j = 0; j < 4; j++)
                    paccum[i][j] = fmaf(av[i], bv[j], paccum[i][j]);
        }
        __syncthreads();
    }

    if (tx < 8) {
        #pragma unroll
        for (int j = 0; j < 8; j++) red[ty][tx * 8 + j] = esum[j];
    }
    __syncthreads();
    if (tid < 64) {
        float s = 0.f;
        for (int t = 0; t < 16; t++) s += red[t][tid];
        cs[tid] = s;
    }
    __syncthreads();
    if (tid == 0) {
        float tot = 0.f;
        for (int i = 0; i < 64; i++) tot += cs[i];
        total_s = tot;
    }
    __syncthreads();
    size_t base = (size_t)(b * 2 + side) * 4 + d;
    if (tid < 64) relsum[base * 64 + tid] = cs[tid] / total_s;

    float* ptout = pt + base * 4096;
    #pragma unroll
    for (int i = 0; i < 4; i++)
        #pragma unroll
        for (int j = 0; j < 4; j++)
            ptout[(size_t)(ty * 4 + i) * 64 + tx * 4 + j] = paccum[i][j];
}

// ---------------- finalize per (b,d): vectorized LDS matmuls, atomicAdd into out ----------------
__global__ __launch_bounds__(256) void finalize2_kernel(
    const float* __restrict__ relsum, const float* __restrict__ pt,
    const float* __restrict__ p_rel_xj, const float* __restrict__ p_rel_xi,
    const double* __restrict__ part, const float* __restrict__ stats, int ppb,
    float* __restrict__ out)
{
    int blk = blockIdx.x;
    int b = blk >> 2, d = blk & 3;
    int tid = threadIdx.x, tx = tid & 15, ty = tid >> 4;
    __shared__ __align__(16) float Ptj[64][68], Pti[64][68], Wr[64][68];
    __shared__ float red[16][64];
    __shared__ float fj[64], fi[64];
    __shared__ float rs[256], rq[256];
    __shared__ float bc[1];
    __shared__ float sstat[2];

    if (ppb > 0) {
        // reduce ppb fp64 partial pairs for batch b (ppb = 32, power of two)
        if (tid < ppb) {
            double s = part[(size_t)(b * ppb + tid) * 2];
            double sq = part[(size_t)(b * ppb + tid) * 2 + 1];
            for (int off = 1; off < ppb; off <<= 1) {
                s += __shfl_xor(s, off, 64);
                sq += __shfl_xor(sq, off, 64);
            }
            if (tid == 0) {
                double n = 262144.0;
                double mean = s / n;
                double var = (sq - n * mean * mean) / (n - 1.0);
                sstat[0] = (float)(mean * 64.0);
                sstat[1] = (float)(sqrt(var) * 64.0);
            }
        }
    } else if (tid == 0) {
        sstat[0] = stats[b * 2 + 0];
        sstat[1] = stats[b * 2 + 1];
    }

    const float* ptj = pt + ((size_t)(b * 2 + 0) * 4 + d) * 4096;
    const float* pti = pt + ((size_t)(b * 2 + 1) * 4 + d) * 4096;
    for (int it = 0; it < 16; it++) {
        int idx = tid + it * 256;
        Ptj[idx >> 6][idx & 63] = ptj[idx];
        Pti[idx >> 6][idx & 63] = pti[idx];
    }
    __syncthreads();
    float x_mean = sstat[0];
    float x_std  = sstat[1];

    for (int s = 0; s < 2; s++) {
        const float* prel = (s == 0) ? (p_rel_xj + (size_t)d * 4096)
                                     : (p_rel_xi + (size_t)d * 4096);
        for (int it = 0; it < 16; it++) {
            int idx = tid + it * 256;
            Wr[idx >> 6][idx & 63] = prel[idx];
        }
        __syncthreads();
        const float (*Pt)[68] = (s == 0) ? Ptj : Pti;
        float q[4][4];
        #pragma unroll
        for (int i = 0; i < 4; i++)
            #pragma unroll
            for (int j = 0; j < 4; j++) q[i][j] = 0.f;
        for (int r = 0; r < 64; r++) {
            float4 bv = *(const float4*)&Wr[r][tx * 4];
            #pragma unroll
            for (int i = 0; i < 4; i++) {
                float a = Pt[ty * 4 + i][r];
                q[i][0] = fmaf(a, bv.x, q[i][0]);
                q[i][1] = fmaf(a, bv.y, q[i][1]);
                q[i][2] = fmaf(a, bv.z, q[i][2]);
                q[i][3] = fmaf(a, bv.w, q[i][3]);
            }
        }
        float cpart[4];
        #pragma unroll
        for (int j = 0; j < 4; j++)
            cpart[j] = __expf(q[0][j]) + __expf(q[1][j]) + __expf(q[2][j]) + __expf(q[3][j]);
        #pragma unroll
        for (int j = 0; j < 4; j++) red[ty][tx * 4 + j] = cpart[j];
        __syncthreads();
        float* ftgt = (s == 0) ? fj : fi;
        if (tid < 64) {
            float cssum = 0.f;
            for (int t = 0; t < 16; t++) cssum += red[t][tid];
            ftgt[tid] = cssum;
        }
        __syncthreads();
        if (tid == 0) {
            float tot = 0.f;
            for (int i = 0; i < 64; i++) tot += ftgt[i];
            bc[0] = tot;
        }
        __syncthreads();
        if (tid < 64) {
            float prel_sum = ftgt[tid] / bc[0];
            float orel = relsum[((size_t)(b * 2 + s) * 4 + d) * 64 + tid];
            ftgt[tid] = sqrtf(orel / prel_sum);
        }
        __syncthreads();
    }

    float v[4][4];
    float psum = 0.f, psq = 0.f;
    #pragma unroll
    for (int i = 0; i < 4; i++) {
        int r = ty * 4 + i;
        #pragma unroll
        for (int j = 0; j < 4; j++) {
            int c = tx * 4 + j;
            float val = Ptj[r][c] * fj[r] + Pti[c][r] * fi[c];
            v[i][j] = val; psum += val; psq += val * val;
        }
    }
    rs[tid] = psum; rq[tid] = psq;
    __syncthreads();
    for (int st = 128; st > 0; st >>= 1) {
        if (tid < st) { rs[tid] += rs[tid + st]; rq[tid] += rq[tid + st]; }
        __syncthreads();
    }
    float mean = rs[0] / 4096.f;
    float var = (rq[0] - 4096.f * mean * mean) / 4095.f;
    float inv = 1.0f / (sqrtf(var) + EPSF);
    float* ob = out + (size_t)b * 4096;
    #pragma unroll
    for (int i = 0; i < 4; i++)
        #pragma unroll
        for (int j = 0; j < 4; j++)
            atomicAdd(&ob[(size_t)(ty * 4 + i) * 64 + tx * 4 + j],
                      (v[i][j] - mean) * inv * x_std + x_mean);
}

extern "C" void kernel_launch(void* const* d_in, const int* in_sizes, int n_in,
                              void* d_out, int out_size, void* d_ws, size_t ws_size,
                              hipStream_t stream) {
    const float* x        = (const float*)d_in[0];
    const float* o_xj     = (const float*)d_in[1];
    const float* o_xi     = (const float*)d_in[2];
    const float* p_xj     = (const float*)d_in[3];
    const float* p_xi     = (const float*)d_in[4];
    const float* o_rel_xj = (const float*)d_in[5];
    const float* o_rel_xi = (const float*)d_in[6];
    const float* p_rel_xj = (const float*)d_in[7];
    const float* p_rel_xi = (const float*)d_in[8];
    float* out = (float*)d_out;

    char* ws = (char*)d_ws;
    float*  stats  = (float*)(ws + 0);           // 1024
    float*  relsum = (float*)(ws + 1024);        // 262144
    float*  pt     = (float*)(ws + 263168);      // 16777216
    double* spartF = (double*)(ws + 17040384);   // 65536 used (4096*2 doubles)
    short*  xbf    = (short*)(ws + 17171456);    // 67108864
    short*  xtbf   = (short*)(ws + 84280320);    // 67108864
    short*  wcat   = (short*)(ws + 151389184);   // 1048576
    short*  wptb   = (short*)(ws + 152437760);   // 524288 -> end 152962048
    double* spartS = (double*)(ws + 17040384);   // fallback reuses spartF slot

    hipMemsetAsync(d_out, 0, (size_t)out_size * sizeof(float), stream);

    const size_t FAST_NEED = 152962048;
    if (ws_size >= FAST_NEED) {
        prep_kernel<<<4480, 256, 0, stream>>>(x, o_xj, o_xi, p_xj, p_xi,
                                              o_rel_xj, o_rel_xi,
                                              xbf, xtbf, spartF, wcat, wptb);
        main_mfma_kernel<<<1024, 256, 0, stream>>>(xbf, xtbf, wcat, wptb, relsum, pt);
        finalize2_kernel<<<512, 256, 0, stream>>>(relsum, pt, p_rel_xj, p_rel_xi,
                                                  spartF, stats, 32, out);
    } else {
        if (ws_size >= 17171456) {
            stats_p1<<<512, 256, 0, stream>>>(x, spartS);
            stats_p2<<<1, 128, 0, stream>>>(spartS, stats, 4);
        } else {
            double* sp = (double*)(ws + 263168);
            stats_p1<<<512, 256, 0, stream>>>(x, sp);
            stats_p2<<<1, 128, 0, stream>>>(sp, stats, 4);
        }
        fused_proj_kernel<<<1024, 256, 0, stream>>>(x, o_xj, o_xi, p_xj, p_xi,
                                                    o_rel_xj, o_rel_xi, relsum, pt);
        finalize2_kernel<<<512, 256, 0, stream>>>(relsum, pt, p_rel_xj, p_rel_xi,
                                                  (const double*)nullptr, stats, 0, out);
    }
}